// Round 1
// baseline (275.211 us; speedup 1.0000x reference)
//
#include <hip/hip_runtime.h>
#include <math.h>

#define NTOK   16384
#define INF    2048
#define OUTF   2048
#define SR     45
#define SRP    48      // padded rank
#define RANK   8
#define BLK    64
#define NBLK   32

// ---------------------------------------------------------------------------
// K1: t_part[split][tok][48] = x[tok, Kslice] @ shared_in[Kslice, 45]
//     hidden_ws[tok][b][r]   = x_block(tok,b) @ rule_in[rid]   (b owned by split)
// grid = 64 token-tiles * nsplit; block = 256 threads, thread-per-token.
// ---------------------------------------------------------------------------
__global__ __launch_bounds__(256, 2)
void k1_tpart_hidden(const float* __restrict__ x,
                     const int*   __restrict__ rule_ids,
                     const float* __restrict__ shared_in,
                     const float* __restrict__ rule_in,
                     float* __restrict__ t_part,
                     float* __restrict__ hidden_ws,
                     int nsplit)
{
    __shared__ __align__(16) float xs[256 * 68];   // 256 tokens x 64 cols, pitch 68
    __shared__ __align__(16) float ss[64 * SRP];   // 64 k-rows x 48 (padded)

    const int tid   = threadIdx.x;
    const int bid   = blockIdx.x;
    const int tile  = bid / nsplit;
    const int split = bid - tile * nsplit;
    const int tok0  = tile << 8;            // *256
    const int K_per = INF / nsplit;
    const int chunks = K_per >> 6;
    const int k_base = split * K_per;

    const int tok = tok0 + tid;
    const int rid = rule_ids[tok];
    const float* __restrict__ rin = rule_in + (size_t)rid * (BLK * RANK);

    // zero the padded cols 45..47 of ss once (staging only writes c<45)
    if (tid < 192) {
        int r = tid / 3;
        int c = SR + (tid - r * 3);
        ss[r * SRP + c] = 0.0f;
    }

    float acc[SRP];
#pragma unroll
    for (int i = 0; i < SRP; ++i) acc[i] = 0.0f;

    for (int ch = 0; ch < chunks; ++ch) {
        const int ks = k_base + (ch << 6);
        __syncthreads();
        // stage x chunk [256 tok][64 cols] -> xs (pitch 68), coalesced float4
#pragma unroll
        for (int u = 0; u < 16; ++u) {
            int f  = tid + (u << 8);        // float4 index 0..4095
            int n  = f >> 4;                // 16 float4 per row
            int c4 = f & 15;
            float4 v = *reinterpret_cast<const float4*>(
                x + (size_t)(tok0 + n) * INF + ks + (c4 << 2));
            *reinterpret_cast<float4*>(&xs[n * 68 + (c4 << 2)]) = v;
        }
        // stage shared_in chunk rows ks..ks+63, cols 0..44
        for (int idx = tid; idx < 64 * SR; idx += 256) {
            int r = idx / SR;
            int c = idx - r * SR;
            ss[r * SRP + c] = shared_in[(size_t)(ks + r) * SR + c];
        }
        __syncthreads();

        float h[RANK];
#pragma unroll
        for (int r = 0; r < RANK; ++r) h[r] = 0.0f;

#pragma unroll 2
        for (int c4 = 0; c4 < 16; ++c4) {
            const float4 xq = *reinterpret_cast<const float4*>(&xs[tid * 68 + (c4 << 2)]);
            const float xv4[4] = {xq.x, xq.y, xq.z, xq.w};
#pragma unroll
            for (int e = 0; e < 4; ++e) {
                const float xv = xv4[e];
                const int c = (c4 << 2) + e;
                const float* __restrict__ srow = &ss[c * SRP];
#pragma unroll
                for (int q = 0; q < 12; ++q) {
                    const float4 sv = *reinterpret_cast<const float4*>(&srow[q << 2]);
                    acc[(q << 2) + 0] = fmaf(xv, sv.x, acc[(q << 2) + 0]);
                    acc[(q << 2) + 1] = fmaf(xv, sv.y, acc[(q << 2) + 1]);
                    acc[(q << 2) + 2] = fmaf(xv, sv.z, acc[(q << 2) + 2]);
                    acc[(q << 2) + 3] = fmaf(xv, sv.w, acc[(q << 2) + 3]);
                }
                const float4 r0 = *reinterpret_cast<const float4*>(&rin[c << 3]);
                const float4 r1 = *reinterpret_cast<const float4*>(&rin[(c << 3) + 4]);
                h[0] = fmaf(xv, r0.x, h[0]);
                h[1] = fmaf(xv, r0.y, h[1]);
                h[2] = fmaf(xv, r0.z, h[2]);
                h[3] = fmaf(xv, r0.w, h[3]);
                h[4] = fmaf(xv, r1.x, h[4]);
                h[5] = fmaf(xv, r1.y, h[5]);
                h[6] = fmaf(xv, r1.z, h[6]);
                h[7] = fmaf(xv, r1.w, h[7]);
            }
        }
        // write this chunk's hidden block (b fully reduced inside chunk)
        const int b = ks >> 6;
        float* __restrict__ hp = hidden_ws + (size_t)tok * (NBLK * RANK) + (b << 3);
        *reinterpret_cast<float4*>(hp)     = make_float4(h[0], h[1], h[2], h[3]);
        *reinterpret_cast<float4*>(hp + 4) = make_float4(h[4], h[5], h[6], h[7]);
    }

    // write t partial (48 floats, cols 45..47 are exact zeros)
    float* __restrict__ tp = t_part + ((size_t)split * NTOK + tok) * SRP;
#pragma unroll
    for (int q = 0; q < 12; ++q) {
        *reinterpret_cast<float4*>(tp + (q << 2)) =
            make_float4(acc[(q << 2) + 0], acc[(q << 2) + 1],
                        acc[(q << 2) + 2], acc[(q << 2) + 3]);
    }
}

// ---------------------------------------------------------------------------
// K2: out = t @ shared_out + sel .* (hidden @ rule_out[rid])
// grid = (512 token-tiles of 32) x (4 col-tiles of 512); block 256 threads.
// thread = (tg = tid>>6 owns 8 tokens, cl = tid&63); 8 tok x 8 col registers.
// ---------------------------------------------------------------------------
__global__ __launch_bounds__(256, 2)
void k2_out(const float* __restrict__ t_part,
            const float* __restrict__ hidden_ws,
            const int*   __restrict__ rule_ids,
            const float* __restrict__ shared_out,
            const float* __restrict__ rule_out,
            const float* __restrict__ logits,
            float* __restrict__ out,
            int nsplit)
{
    __shared__ __align__(16) float t_lds[32 * SRP];      // 6 KB
    __shared__ __align__(16) float h_lds[32 * NBLK * RANK]; // 32 KB
    __shared__ float sel_lds[32 * NBLK];                 // 4 KB
    __shared__ int   rid_lds[32];

    const int tid  = threadIdx.x;
    const int bid  = blockIdx.x;
    const int tok0 = (bid >> 2) << 5;    // *32
    const int col0 = (bid & 3) << 9;     // *512

    // stage t (sum partials over splits)
    for (int idx = tid; idx < 32 * SRP; idx += 256) {
        int n = idx / SRP;
        int k = idx - n * SRP;
        const float* tp = t_part + (size_t)(tok0 + n) * SRP + k;
        float s = 0.0f;
        for (int sp = 0; sp < nsplit; ++sp) s += tp[(size_t)sp * NTOK * SRP];
        t_lds[idx] = s;
    }
    // stage hidden [32 tok][256]
#pragma unroll
    for (int u = 0; u < 8; ++u) {
        int f = tid + (u << 8);          // float4 index, row n = f>>6
        *reinterpret_cast<float4*>(&h_lds[f << 2]) =
            *reinterpret_cast<const float4*>(
                hidden_ws + (size_t)(tok0 + (f >> 6)) * (NBLK * RANK) + ((f & 63) << 2));
    }
    if (tid < 32) {
        rid_lds[tid] = rule_ids[tok0 + tid];
        // per-token softmax over 32 block logits, temp = sqrt(32)
        const float invT = 5.65685424949238f;
        const int r = rule_ids[tok0 + tid];
        const float* lg = logits + (size_t)r * NBLK;
        float m = -1e30f;
        for (int b = 0; b < NBLK; ++b) m = fmaxf(m, lg[b] * invT);
        float s = 0.0f;
        for (int b = 0; b < NBLK; ++b) {
            float e = expf(lg[b] * invT - m);
            sel_lds[tid * NBLK + b] = e;
            s += e;
        }
        float inv = 1.0f / s;
        for (int b = 0; b < NBLK; ++b) sel_lds[tid * NBLK + b] *= inv;
    }
    __syncthreads();

    const int tg = tid >> 6;
    const int cl = tid & 63;

    float acc[8][8];
#pragma unroll
    for (int n = 0; n < 8; ++n)
#pragma unroll
        for (int u = 0; u < 8; ++u) acc[n][u] = 0.0f;

    // main GEMM: t[32x45] @ shared_out[45 x 512-tile]
#pragma unroll 3
    for (int k = 0; k < SR; ++k) {
        float tv[8];
#pragma unroll
        for (int n = 0; n < 8; ++n) tv[n] = t_lds[((tg << 3) + n) * SRP + k];
        const float* __restrict__ so = shared_out + (size_t)k * OUTF + col0 + cl;
        float sv[8];
#pragma unroll
        for (int u = 0; u < 8; ++u) sv[u] = so[u << 6];
#pragma unroll
        for (int n = 0; n < 8; ++n)
#pragma unroll
            for (int u = 0; u < 8; ++u) acc[n][u] = fmaf(tv[n], sv[u], acc[n][u]);
    }

    // adapter: sel[b] * (hidden[tok,b,:] . rule_out[rid,:,cl])
    const int b0 = (bid & 3) << 3;       // first of 8 blocks in this col tile
#pragma unroll
    for (int n = 0; n < 8; ++n) {
        const int tokl = (tg << 3) + n;
        const int rid = rid_lds[tokl];
        const float* __restrict__ ro = rule_out + (size_t)rid * (RANK * BLK) + cl;
        float rv[RANK];
#pragma unroll
        for (int r = 0; r < RANK; ++r) rv[r] = ro[r << 6];
#pragma unroll
        for (int u = 0; u < 8; ++u) {
            const float* hp = &h_lds[tokl * (NBLK * RANK) + ((b0 + u) << 3)];
            const float4 h0 = *reinterpret_cast<const float4*>(hp);
            const float4 h1 = *reinterpret_cast<const float4*>(hp + 4);
            float s = h0.x * rv[0] + h0.y * rv[1] + h0.z * rv[2] + h0.w * rv[3]
                    + h1.x * rv[4] + h1.y * rv[5] + h1.z * rv[6] + h1.w * rv[7];
            acc[n][u] = fmaf(sel_lds[tokl * NBLK + b0 + u], s, acc[n][u]);
        }
    }

    // store
#pragma unroll
    for (int n = 0; n < 8; ++n) {
        float* __restrict__ op = out + (size_t)(tok0 + (tg << 3) + n) * OUTF + col0 + cl;
#pragma unroll
        for (int u = 0; u < 8; ++u) op[u << 6] = acc[n][u];
    }
}

extern "C" void kernel_launch(void* const* d_in, const int* in_sizes, int n_in,
                              void* d_out, int out_size, void* d_ws, size_t ws_size,
                              hipStream_t stream)
{
    const float* x          = (const float*)d_in[0];
    const int*   rule_ids   = (const int*)  d_in[1];
    const float* shared_in  = (const float*)d_in[2];
    const float* shared_out = (const float*)d_in[3];
    const float* rule_in    = (const float*)d_in[4];
    const float* rule_out   = (const float*)d_in[5];
    const float* logits     = (const float*)d_in[6];
    float* out = (float*)d_out;

    const size_t hid_bytes = (size_t)NTOK * NBLK * RANK * sizeof(float); // 16.8 MB
    int nsplit = 8;
    while (nsplit > 1 &&
           (size_t)nsplit * NTOK * SRP * sizeof(float) + hid_bytes > ws_size)
        nsplit >>= 1;

    float* t_part    = (float*)d_ws;
    float* hidden_ws = (float*)((char*)d_ws + (size_t)nsplit * NTOK * SRP * sizeof(float));

    k1_tpart_hidden<<<dim3(64 * nsplit), dim3(256), 0, stream>>>(
        x, rule_ids, shared_in, rule_in, t_part, hidden_ws, nsplit);
    k2_out<<<dim3(2048), dim3(256), 0, stream>>>(
        t_part, hidden_ws, rule_ids, shared_out, rule_out, logits, out, nsplit);
}

// Round 2
// 250.064 us; speedup vs baseline: 1.1006x; 1.1006x over previous
//
#include <hip/hip_runtime.h>
#include <math.h>

#define NTOK  16384
#define INF   2048
#define OUTF  2048
#define SR    45
#define SRP   48
#define RANK  8
#define BLK   64
#define NBLK  32
#define NRULE 256

// ---------------------------------------------------------------------------
// kprep: block 0 = counting sort of tokens by rule (perm, srid);
//        block 1 = repack shared_in -> [2048][48] padded, sel_table[256][32].
// ---------------------------------------------------------------------------
__global__ void kprep(const int* __restrict__ rule_ids,
                      const float* __restrict__ shared_in,
                      const float* __restrict__ logits,
                      float* __restrict__ ssp,
                      float* __restrict__ sel_t,
                      int* __restrict__ perm,
                      int* __restrict__ srid)
{
    const int tid = threadIdx.x;
    if (blockIdx.x == 0) {
        __shared__ int hist[NRULE];
        __shared__ int scan[NRULE];
        __shared__ int base[NRULE];
        if (tid < NRULE) hist[tid] = 0;
        __syncthreads();
        for (int i = tid; i < NTOK; i += 1024) atomicAdd(&hist[rule_ids[i]], 1);
        __syncthreads();
        if (tid < NRULE) scan[tid] = hist[tid];
        for (int off = 1; off < NRULE; off <<= 1) {
            __syncthreads();
            int v = (tid < NRULE && tid >= off) ? scan[tid - off] : 0;
            __syncthreads();
            if (tid < NRULE) scan[tid] += v;
        }
        __syncthreads();
        if (tid < NRULE) base[tid] = scan[tid] - hist[tid];   // exclusive
        __syncthreads();
        for (int i = tid; i < NTOK; i += 1024) {
            int r = rule_ids[i];
            int p = atomicAdd(&base[r], 1);
            perm[p] = i;
            srid[p] = r;
        }
    } else {
        for (int idx = tid; idx < INF * SRP; idx += 1024) {
            int r = idx / SRP, c = idx - r * SRP;
            ssp[idx] = (c < SR) ? shared_in[r * SR + c] : 0.0f;
        }
        if (tid < NRULE) {
            const float invT = 5.65685424949238f;
            const float* __restrict__ lg = logits + (size_t)tid * NBLK;
            float m = -1e30f;
            for (int b = 0; b < NBLK; ++b) m = fmaxf(m, lg[b] * invT);
            float s = 0.0f;
            for (int b = 0; b < NBLK; ++b) s += expf(lg[b] * invT - m);
            float inv = 1.0f / s;
            for (int b = 0; b < NBLK; ++b)
                sel_t[(size_t)tid * NBLK + b] = expf(lg[b] * invT - m) * inv;
        }
    }
}

// ---------------------------------------------------------------------------
// K1: thread-per-sorted-token. t_part[split][slot][48] = x_row @ ssp_slice,
//     hidden_ws[slot][b][r] accumulated per 64-col block.
// shared_in slice read at uniform addresses (-> scalar loads); rule_in read
// per-lane but tokens are rule-sorted -> near-broadcast.
// ---------------------------------------------------------------------------
__global__ __launch_bounds__(256, 4)
void k1(const float* __restrict__ x,
        const int*   __restrict__ perm,
        const int*   __restrict__ srid,
        const float* __restrict__ ssp,
        const float* __restrict__ rule_in,
        float* __restrict__ t_part,
        float* __restrict__ hidden_ws,
        int nsplit)
{
    __shared__ __align__(16) float xs[256 * 36];   // 36.9 KB, pitch 36

    const int tid   = threadIdx.x;
    const int bid   = blockIdx.x;
    const int tile  = bid / nsplit;
    const int split = bid - tile * nsplit;
    const int tok0  = tile << 8;
    const int K_per = INF / nsplit;
    const int nch   = K_per >> 5;          // chunks of 32 k
    const int k_base = split * K_per;

    const int tok = tok0 + tid;            // sorted slot
    const int rid = srid[tok];
    const float* __restrict__ rin = rule_in + (size_t)rid * (BLK * RANK);

    int prow[8];
#pragma unroll
    for (int u = 0; u < 8; ++u) prow[u] = perm[tok0 + (tid >> 3) + (u << 5)];

    float acc[SRP];
#pragma unroll
    for (int i = 0; i < SRP; ++i) acc[i] = 0.0f;
    float h[RANK];

    for (int ch = 0; ch < nch; ++ch) {
        const int ks = k_base + (ch << 5);
        __syncthreads();
        // stage 256 rows x 32 cols; lanes 0..7 cover one row (128 B)
#pragma unroll
        for (int u = 0; u < 8; ++u) {
            float4 v = *reinterpret_cast<const float4*>(
                x + (size_t)prow[u] * INF + ks + ((tid & 7) << 2));
            *reinterpret_cast<float4*>(
                &xs[((tid >> 3) + (u << 5)) * 36 + ((tid & 7) << 2)]) = v;
        }
        __syncthreads();

        if ((ch & 1) == 0) {
#pragma unroll
            for (int r = 0; r < RANK; ++r) h[r] = 0.0f;
        }
        const int kb0 = (ch & 1) << 5;

#pragma unroll 2
        for (int k4 = 0; k4 < 8; ++k4) {
            const float4 xq = *reinterpret_cast<const float4*>(&xs[tid * 36 + (k4 << 2)]);
            const float xv4[4] = {xq.x, xq.y, xq.z, xq.w};
#pragma unroll
            for (int e = 0; e < 4; ++e) {
                const float xv = xv4[e];
                const int k = (k4 << 2) + e;
                const float* __restrict__ sp = ssp + (size_t)(ks + k) * SRP; // uniform
#pragma unroll
                for (int q = 0; q < 12; ++q) {
                    const float4 sv = *reinterpret_cast<const float4*>(sp + (q << 2));
                    acc[(q << 2) + 0] = fmaf(xv, sv.x, acc[(q << 2) + 0]);
                    acc[(q << 2) + 1] = fmaf(xv, sv.y, acc[(q << 2) + 1]);
                    acc[(q << 2) + 2] = fmaf(xv, sv.z, acc[(q << 2) + 2]);
                    acc[(q << 2) + 3] = fmaf(xv, sv.w, acc[(q << 2) + 3]);
                }
                const int kb = kb0 + k;
                const float4 r0 = *reinterpret_cast<const float4*>(rin + (kb << 3));
                const float4 r1 = *reinterpret_cast<const float4*>(rin + (kb << 3) + 4);
                h[0] = fmaf(xv, r0.x, h[0]);
                h[1] = fmaf(xv, r0.y, h[1]);
                h[2] = fmaf(xv, r0.z, h[2]);
                h[3] = fmaf(xv, r0.w, h[3]);
                h[4] = fmaf(xv, r1.x, h[4]);
                h[5] = fmaf(xv, r1.y, h[5]);
                h[6] = fmaf(xv, r1.z, h[6]);
                h[7] = fmaf(xv, r1.w, h[7]);
            }
        }

        if (ch & 1) {
            const int b = ks >> 6;
            float* __restrict__ hp = hidden_ws + (size_t)tok * (NBLK * RANK) + (b << 3);
            *reinterpret_cast<float4*>(hp)     = make_float4(h[0], h[1], h[2], h[3]);
            *reinterpret_cast<float4*>(hp + 4) = make_float4(h[4], h[5], h[6], h[7]);
        }
    }

    float* __restrict__ tp = t_part + ((size_t)split * NTOK + tok) * SRP;
#pragma unroll
    for (int q = 0; q < 12; ++q)
        *reinterpret_cast<float4*>(tp + (q << 2)) =
            make_float4(acc[(q << 2) + 0], acc[(q << 2) + 1],
                        acc[(q << 2) + 2], acc[(q << 2) + 3]);
}

// ---------------------------------------------------------------------------
// K2: out[perm[slot]] = t @ shared_out + (sel.*hidden) @ rule_out
// block = 32 sorted tokens x 512 cols; thread: tg=tid>>6 owns 8 tokens,
// lane cl owns 8 CONTIGUOUS cols -> all global traffic is float4.
// ---------------------------------------------------------------------------
__global__ __launch_bounds__(256, 4)
void k2(const float* __restrict__ t_part,
        const float* __restrict__ hidden_ws,
        const int*   __restrict__ perm,
        const int*   __restrict__ srid,
        const float* __restrict__ shared_out,
        const float* __restrict__ rule_out,
        const float* __restrict__ sel_t,
        float* __restrict__ out,
        int nsplit)
{
    __shared__ __align__(16) float t_lds[SRP * 36];  // [k][tok], pitch 36
    __shared__ __align__(16) float hs_lds[32 * 64];  // [tok][8 blk x 8 r], sel folded
    __shared__ int perm_lds[32];
    __shared__ int srid_lds[32];

    const int tid  = threadIdx.x;
    const int bid  = blockIdx.x;
    const int tok0 = (bid >> 2) << 5;
    const int ct   = bid & 3;
    const int col0 = ct << 9;
    const int b0   = ct << 3;

    if (tid < 32) {
        perm_lds[tid] = perm[tok0 + tid];
        srid_lds[tid] = srid[tok0 + tid];
    }

    // stage t (sum split partials), transposed to [k][tok]
    for (int idx = tid; idx < 32 * SRP; idx += 256) {
        int n = idx / SRP, k = idx - n * SRP;
        const float* __restrict__ tp = t_part + (size_t)(tok0 + n) * SRP + k;
        float s = 0.0f;
        for (int sp_ = 0; sp_ < nsplit; ++sp_) s += tp[(size_t)sp_ * NTOK * SRP];
        t_lds[k * 36 + n] = s;
    }
    // stage this col-tile's hidden slice, scaled by sel
#pragma unroll
    for (int u = 0; u < 2; ++u) {
        int f  = tid + (u << 8);       // float4 index 0..511
        int n  = f >> 4;               // token 0..31
        int j4 = f & 15;               // float4 within 64-float slice
        int b  = b0 + (j4 >> 1);
        int r  = srid[tok0 + n];
        float sel = sel_t[(size_t)r * NBLK + b];
        float4 v = *reinterpret_cast<const float4*>(
            hidden_ws + (size_t)(tok0 + n) * (NBLK * RANK) + (b0 << 3) + (j4 << 2));
        v.x *= sel; v.y *= sel; v.z *= sel; v.w *= sel;
        *reinterpret_cast<float4*>(&hs_lds[(n << 6) + (j4 << 2)]) = v;
    }
    __syncthreads();

    const int tg = tid >> 6;
    const int cl = tid & 63;
    const float* __restrict__ so_base = shared_out + col0 + (cl << 3);

    float acc[8][8];
#pragma unroll
    for (int n = 0; n < 8; ++n)
#pragma unroll
        for (int e = 0; e < 8; ++e) acc[n][e] = 0.0f;

#pragma unroll 3
    for (int k = 0; k < SR; ++k) {
        const float4 ta = *reinterpret_cast<const float4*>(&t_lds[k * 36 + (tg << 3)]);
        const float4 tb = *reinterpret_cast<const float4*>(&t_lds[k * 36 + (tg << 3) + 4]);
        const float tv[8] = {ta.x, ta.y, ta.z, ta.w, tb.x, tb.y, tb.z, tb.w};
        const float4 s0 = *reinterpret_cast<const float4*>(so_base + (size_t)k * OUTF);
        const float4 s1 = *reinterpret_cast<const float4*>(so_base + (size_t)k * OUTF + 4);
        const float sv[8] = {s0.x, s0.y, s0.z, s0.w, s1.x, s1.y, s1.z, s1.w};
#pragma unroll
        for (int n = 0; n < 8; ++n)
#pragma unroll
            for (int e = 0; e < 8; ++e)
                acc[n][e] = fmaf(tv[n], sv[e], acc[n][e]);
    }

    // adapter: lane's 8 cols live in ONE 64-col block b0+bl
    const int bl = cl >> 3;
    const int c0 = (cl & 7) << 3;
#pragma unroll
    for (int n = 0; n < 8; ++n) {
        const int tokl = (tg << 3) + n;
        const float* __restrict__ ro =
            rule_out + (size_t)srid_lds[tokl] * (RANK * BLK) + c0;
        const float4 h0 = *reinterpret_cast<const float4*>(&hs_lds[(tokl << 6) + (bl << 3)]);
        const float4 h1 = *reinterpret_cast<const float4*>(&hs_lds[(tokl << 6) + (bl << 3) + 4]);
        const float hv[8] = {h0.x, h0.y, h0.z, h0.w, h1.x, h1.y, h1.z, h1.w};
#pragma unroll
        for (int r = 0; r < 8; ++r) {
            const float4 r0 = *reinterpret_cast<const float4*>(ro + (r << 6));
            const float4 r1 = *reinterpret_cast<const float4*>(ro + (r << 6) + 4);
            acc[n][0] = fmaf(hv[r], r0.x, acc[n][0]);
            acc[n][1] = fmaf(hv[r], r0.y, acc[n][1]);
            acc[n][2] = fmaf(hv[r], r0.z, acc[n][2]);
            acc[n][3] = fmaf(hv[r], r0.w, acc[n][3]);
            acc[n][4] = fmaf(hv[r], r1.x, acc[n][4]);
            acc[n][5] = fmaf(hv[r], r1.y, acc[n][5]);
            acc[n][6] = fmaf(hv[r], r1.z, acc[n][6]);
            acc[n][7] = fmaf(hv[r], r1.w, acc[n][7]);
        }
    }

    // scattered row store (2 KB contiguous per token row)
#pragma unroll
    for (int n = 0; n < 8; ++n) {
        const int tokl = (tg << 3) + n;
        float* __restrict__ op = out + (size_t)perm_lds[tokl] * OUTF + col0 + (cl << 3);
        *reinterpret_cast<float4*>(op)     = make_float4(acc[n][0], acc[n][1], acc[n][2], acc[n][3]);
        *reinterpret_cast<float4*>(op + 4) = make_float4(acc[n][4], acc[n][5], acc[n][6], acc[n][7]);
    }
}

extern "C" void kernel_launch(void* const* d_in, const int* in_sizes, int n_in,
                              void* d_out, int out_size, void* d_ws, size_t ws_size,
                              hipStream_t stream)
{
    const float* x          = (const float*)d_in[0];
    const int*   rule_ids   = (const int*)  d_in[1];
    const float* shared_in  = (const float*)d_in[2];
    const float* shared_out = (const float*)d_in[3];
    const float* rule_in    = (const float*)d_in[4];
    const float* rule_out   = (const float*)d_in[5];
    const float* logits     = (const float*)d_in[6];
    float* out = (float*)d_out;

    // ws layout
    const size_t ssp_b  = (size_t)INF * SRP * sizeof(float);      // 393216
    const size_t sel_b  = (size_t)NRULE * NBLK * sizeof(float);   // 32768
    const size_t perm_b = (size_t)NTOK * sizeof(int);             // 65536
    const size_t hid_b  = (size_t)NTOK * NBLK * RANK * sizeof(float); // 16.78 MB
    const size_t fixed  = ssp_b + sel_b + 2 * perm_b + hid_b;

    int nsplit = 8;
    while (nsplit > 1 &&
           fixed + (size_t)nsplit * NTOK * SRP * sizeof(float) > ws_size)
        nsplit >>= 1;

    char* p = (char*)d_ws;
    float* ssp       = (float*)p;                 p += ssp_b;
    float* sel_t     = (float*)p;                 p += sel_b;
    int*   perm      = (int*)p;                   p += perm_b;
    int*   srid      = (int*)p;                   p += perm_b;
    float* hidden_ws = (float*)p;                 p += hid_b;
    float* t_part    = (float*)p;

    kprep<<<dim3(2), dim3(1024), 0, stream>>>(rule_ids, shared_in, logits,
                                              ssp, sel_t, perm, srid);
    k1<<<dim3(64 * nsplit), dim3(256), 0, stream>>>(
        x, perm, srid, ssp, rule_in, t_part, hidden_ws, nsplit);
    k2<<<dim3(2048), dim3(256), 0, stream>>>(
        t_part, hidden_ws, perm, srid, shared_out, rule_out, sel_t, out, nsplit);
}

// Round 3
// 158.379 us; speedup vs baseline: 1.7377x; 1.5789x over previous
//
#include <hip/hip_runtime.h>
#include <math.h>

#define NTOK  16384
#define INF   2048
#define OUTF  2048
#define SR    45
#define RANK  8
#define BLK   64
#define NBLK  32
#define NRULE 256
#define MAXSLOT (NTOK + NRULE * 15)   // 20224, divisible by 32
#define NTILE (MAXSLOT / 32)          // 632 token-tiles of 32

typedef __attribute__((ext_vector_type(8))) short bf16x8;
typedef __attribute__((ext_vector_type(4))) float f32x4;

__device__ inline unsigned short f2bf(float f) {
    union { float f; unsigned u; } v; v.f = f;
    unsigned r = v.u + 0x7FFFu + ((v.u >> 16) & 1u);
    return (unsigned short)(r >> 16);
}

// ---------------------------------------------------------------------------
// prep A: counting sort with per-rule padding to multiples of 16, sel table.
// Every 16-slot strip is rule-uniform (pad slots: perm=-1, srid=group rule).
// ---------------------------------------------------------------------------
__global__ void kprep_sort(const int* __restrict__ rule_ids,
                           const float* __restrict__ logits,
                           int* __restrict__ perm_p,
                           int* __restrict__ srid_p,
                           float* __restrict__ sel_t)
{
    __shared__ int hist[NRULE];
    __shared__ int padscan[NRULE];
    __shared__ int pstart[NRULE];
    __shared__ int cnt[NRULE];
    const int tid = threadIdx.x;

    if (tid < NRULE) { hist[tid] = 0; cnt[tid] = 0; }
    __syncthreads();
    for (int i = tid; i < NTOK; i += 1024) atomicAdd(&hist[rule_ids[i]], 1);
    __syncthreads();
    if (tid < NRULE) padscan[tid] = ((hist[tid] + 15) >> 4) << 4;
    for (int off = 1; off < NRULE; off <<= 1) {
        __syncthreads();
        int v = (tid < NRULE && tid >= off) ? padscan[tid - off] : 0;
        __syncthreads();
        if (tid < NRULE) padscan[tid] += v;
    }
    __syncthreads();
    if (tid < NRULE) pstart[tid] = padscan[tid] - (((hist[tid] + 15) >> 4) << 4);
    __syncthreads();
    for (int i = tid; i < MAXSLOT; i += 1024) { perm_p[i] = -1; srid_p[i] = 0; }
    __syncthreads();
    for (int i = tid; i < NTOK; i += 1024) {
        int r = rule_ids[i];
        int p = atomicAdd(&cnt[r], 1);
        perm_p[pstart[r] + p] = i;
        srid_p[pstart[r] + p] = r;
    }
    if (tid < NRULE) {
        int r = tid, c = hist[r], pc = ((c + 15) >> 4) << 4;
        for (int q = c; q < pc; ++q) srid_p[pstart[r] + q] = r;
        // softmax table
        const float invT = 5.65685424949238f;
        const float* __restrict__ lg = logits + (size_t)r * NBLK;
        float m = -1e30f;
        for (int b = 0; b < NBLK; ++b) m = fmaxf(m, lg[b] * invT);
        float s = 0.0f;
        for (int b = 0; b < NBLK; ++b) s += expf(lg[b] * invT - m);
        float inv = 1.0f / s;
        for (int b = 0; b < NBLK; ++b)
            sel_t[(size_t)r * NBLK + b] = expf(lg[b] * invT - m) * inv;
    }
}

// ---------------------------------------------------------------------------
// prep B: repack weights into MFMA B-fragment layout (bf16).
// B-frag (16x16x32): lane l holds B[k=(l>>4)*8+j][col=l&15], j=0..7.
// ---------------------------------------------------------------------------
__global__ void kprep_pack(const float* __restrict__ shared_in,
                           const float* __restrict__ shared_out,
                           const float* __restrict__ rule_in,
                           const float* __restrict__ rule_out,
                           unsigned short* __restrict__ ssb,   // [64ch][3nf][64][8]
                           unsigned short* __restrict__ sob,   // [128CF][2kc][64][8]
                           unsigned short* __restrict__ rinf,  // [256][2half][64][8]
                           unsigned short* __restrict__ rof)   // [256][4cf][64][8]
{
    const int gid = blockIdx.x;            // 0..63
    const int tid = gid * 256 + threadIdx.x;
    const int stride = 64 * 256;

    for (int idx = tid; idx < 64 * 3 * 512; idx += stride) {
        int ch = idx / 1536, rem = idx - ch * 1536;
        int nf = rem / 512;
        int l = (rem >> 3) & 63, j = idx & 7;
        int k = ch * 32 + ((l >> 4) << 3) + j;
        int col = nf * 16 + (l & 15);
        ssb[idx] = (col < SR) ? f2bf(shared_in[(size_t)k * SR + col]) : 0;
    }
    for (int idx = tid; idx < 128 * 2 * 512; idx += stride) {
        int CF = idx >> 10;
        int kc = (idx >> 9) & 1;
        int l = (idx >> 3) & 63, j = idx & 7;
        int k = kc * 32 + ((l >> 4) << 3) + j;
        int col = CF * 16 + (l & 15);
        sob[idx] = (k < SR) ? f2bf(shared_out[(size_t)k * OUTF + col]) : 0;
    }
    for (int idx = tid; idx < NRULE * 2 * 512; idx += stride) {
        int rid = idx >> 10;
        int half = (idx >> 9) & 1;
        int l = (idx >> 3) & 63, j = idx & 7;
        int r = l & 15;
        int s = half * 32 + ((l >> 4) << 3) + j;
        rinf[idx] = (r < RANK) ? f2bf(rule_in[(size_t)rid * 512 + s * RANK + r]) : 0;
    }
    for (int idx = tid; idx < NRULE * 4 * 512; idx += stride) {
        int rid = idx >> 11;
        int cf = (idx >> 9) & 3;
        int l = (idx >> 3) & 63, j = idx & 7;
        int k = ((l >> 4) << 3) + j;
        int c = cf * 16 + (l & 15);
        rof[idx] = (k < RANK) ? f2bf(rule_out[(size_t)rid * 512 + k * BLK + c]) : 0;
    }
}

// ---------------------------------------------------------------------------
// K1: t_pad[slot][64] (bf16) = x @ shared_in ; hs[slot][b][r] (bf16, sel-scaled)
// grid 632 tiles of 32 slots; 4 waves = (strip s, K-half h).
// ---------------------------------------------------------------------------
__global__ __launch_bounds__(256)
void k1(const float* __restrict__ x,
        const int* __restrict__ perm_p,
        const int* __restrict__ srid_p,
        const unsigned short* __restrict__ ssb,
        const unsigned short* __restrict__ rinf,
        const float* __restrict__ sel_t,
        unsigned short* __restrict__ t_pad,
        unsigned short* __restrict__ hs)
{
    __shared__ float tred[2][2][16][52];

    const int tid = threadIdx.x;
    const int lane = tid & 63, w = tid >> 6;
    const int s = w & 1, h = w >> 1;
    const int slotbase = blockIdx.x * 32 + s * 16;
    const int row_l = lane & 15, grp = lane >> 4;
    const int myslot = slotbase + row_l;
    const int ptok = perm_p[myslot];
    const int rid = srid_p[myslot];
    const bool valid = (ptok >= 0);

    const float* __restrict__ xr =
        x + (size_t)(valid ? ptok : 0) * INF + h * 1024 + (grp << 3);
    const unsigned short* __restrict__ rbase = rinf + ((size_t)rid * 2) * 512 + lane * 8;
    const int chg0 = h * 32;

    f32x4 aT0 = {0.f, 0.f, 0.f, 0.f};
    f32x4 aT1 = {0.f, 0.f, 0.f, 0.f};
    f32x4 aT2 = {0.f, 0.f, 0.f, 0.f};
    f32x4 aH  = {0.f, 0.f, 0.f, 0.f};

    for (int cp = 0; cp < 16; ++cp) {
#pragma unroll
        for (int sub = 0; sub < 2; ++sub) {
            const int ch = cp * 2 + sub;
            bf16x8 af = {0, 0, 0, 0, 0, 0, 0, 0};
            if (valid) {
                const float4 a0 = *reinterpret_cast<const float4*>(xr + ch * 32);
                const float4 a1 = *reinterpret_cast<const float4*>(xr + ch * 32 + 4);
                af[0] = (short)f2bf(a0.x); af[1] = (short)f2bf(a0.y);
                af[2] = (short)f2bf(a0.z); af[3] = (short)f2bf(a0.w);
                af[4] = (short)f2bf(a1.x); af[5] = (short)f2bf(a1.y);
                af[6] = (short)f2bf(a1.z); af[7] = (short)f2bf(a1.w);
            }
            const unsigned short* __restrict__ sb =
                ssb + ((size_t)(chg0 + ch) * 3) * 512 + lane * 8;
            aT0 = __builtin_amdgcn_mfma_f32_16x16x32_bf16(
                af, *reinterpret_cast<const bf16x8*>(sb), aT0, 0, 0, 0);
            aT1 = __builtin_amdgcn_mfma_f32_16x16x32_bf16(
                af, *reinterpret_cast<const bf16x8*>(sb + 512), aT1, 0, 0, 0);
            aT2 = __builtin_amdgcn_mfma_f32_16x16x32_bf16(
                af, *reinterpret_cast<const bf16x8*>(sb + 1024), aT2, 0, 0, 0);
            aH = __builtin_amdgcn_mfma_f32_16x16x32_bf16(
                af, *reinterpret_cast<const bf16x8*>(rbase + sub * 512), aH, 0, 0, 0);
        }
        // extract hidden for 64-block b (rows = tokens, col = r)
        const int b = h * 16 + cp;
        const float sel = sel_t[rid * NBLK + b];
        if (row_l < RANK) {
            const size_t base = ((size_t)(slotbase + (grp << 2))) * 256 + b * 8 + row_l;
            hs[base]       = f2bf(aH[0] * sel);
            hs[base + 256] = f2bf(aH[1] * sel);
            hs[base + 512] = f2bf(aH[2] * sel);
            hs[base + 768] = f2bf(aH[3] * sel);
        }
        aH[0] = 0.f; aH[1] = 0.f; aH[2] = 0.f; aH[3] = 0.f;
    }

    // cross-wave (K-half) reduction of t via LDS, then bf16 store padded to 64
#pragma unroll
    for (int q = 0; q < 4; ++q) {
        tred[s][h][(grp << 2) + q][0 * 16 + row_l] = aT0[q];
        tred[s][h][(grp << 2) + q][1 * 16 + row_l] = aT1[q];
        tred[s][h][(grp << 2) + q][2 * 16 + row_l] = aT2[q];
    }
    __syncthreads();
    for (int idx = tid; idx < 32 * 64; idx += 256) {
        const int tokl = idx >> 6, c = idx & 63;
        float v = 0.f;
        if (c < 48)
            v = tred[tokl >> 4][0][tokl & 15][c] + tred[tokl >> 4][1][tokl & 15][c];
        t_pad[((size_t)(blockIdx.x * 32 + tokl)) * 64 + c] = f2bf(v);
    }
}

// ---------------------------------------------------------------------------
// K2: out[perm[slot]] = t @ shared_out + hs @ rule_out  (hs already sel-scaled)
// grid 632; 4 waves = (strip s, col-half hcol of 1024).
// ---------------------------------------------------------------------------
__global__ __launch_bounds__(256)
void k2(const unsigned short* __restrict__ t_pad,
        const unsigned short* __restrict__ hs,
        const int* __restrict__ perm_p,
        const int* __restrict__ srid_p,
        const unsigned short* __restrict__ sob,
        const unsigned short* __restrict__ rof,
        float* __restrict__ out)
{
    const int tid = threadIdx.x;
    const int lane = tid & 63, w = tid >> 6;
    const int s = w & 1, hcol = w >> 1;
    const int slotbase = blockIdx.x * 32 + s * 16;
    const int row_l = lane & 15, grp = lane >> 4;

    // t A-fragments (whole wave's K) — registers for the entire kernel
    const unsigned short* __restrict__ tb =
        t_pad + ((size_t)(slotbase + row_l)) * 64 + (grp << 3);
    const bf16x8 at0 = *reinterpret_cast<const bf16x8*>(tb);
    const bf16x8 at1 = *reinterpret_cast<const bf16x8*>(tb + 32);

    const int4 pv = *reinterpret_cast<const int4*>(perm_p + slotbase + (grp << 2));
    const int pvq[4] = {pv.x, pv.y, pv.z, pv.w};
    const int rid_s = srid_p[slotbase];   // strip-uniform

    for (int b_i = 0; b_i < 16; ++b_i) {
        const int b = hcol * 16 + b_i;
        bf16x8 ah = {0, 0, 0, 0, 0, 0, 0, 0};
        if (lane < 16)
            ah = *reinterpret_cast<const bf16x8*>(
                hs + ((size_t)(slotbase + lane)) * 256 + b * 8);
#pragma unroll
        for (int cfb = 0; cfb < 4; ++cfb) {
            const int CF = (b << 2) + cfb;
            f32x4 acc = {0.f, 0.f, 0.f, 0.f};
            const unsigned short* __restrict__ sf = sob + ((size_t)CF * 2) * 512 + lane * 8;
            acc = __builtin_amdgcn_mfma_f32_16x16x32_bf16(
                at0, *reinterpret_cast<const bf16x8*>(sf), acc, 0, 0, 0);
            acc = __builtin_amdgcn_mfma_f32_16x16x32_bf16(
                at1, *reinterpret_cast<const bf16x8*>(sf + 512), acc, 0, 0, 0);
            acc = __builtin_amdgcn_mfma_f32_16x16x32_bf16(
                ah,
                *reinterpret_cast<const bf16x8*>(rof + ((size_t)(rid_s * 4 + cfb)) * 512 + lane * 8),
                acc, 0, 0, 0);
            const int col = (CF << 4) + row_l;
#pragma unroll
            for (int q = 0; q < 4; ++q)
                if (pvq[q] >= 0) out[(size_t)pvq[q] * OUTF + col] = acc[q];
        }
    }
}

extern "C" void kernel_launch(void* const* d_in, const int* in_sizes, int n_in,
                              void* d_out, int out_size, void* d_ws, size_t ws_size,
                              hipStream_t stream)
{
    const float* x          = (const float*)d_in[0];
    const int*   rule_ids   = (const int*)  d_in[1];
    const float* shared_in  = (const float*)d_in[2];
    const float* shared_out = (const float*)d_in[3];
    const float* rule_in    = (const float*)d_in[4];
    const float* rule_out   = (const float*)d_in[5];
    const float* logits     = (const float*)d_in[6];
    float* out = (float*)d_out;

    char* p = (char*)d_ws;
    auto carve = [&p](size_t bytes) {
        char* r = p;
        p += (bytes + 255) & ~(size_t)255;
        return r;
    };
    int*            perm_p = (int*)carve(MAXSLOT * 4);
    int*            srid_p = (int*)carve(MAXSLOT * 4);
    unsigned short* ssb    = (unsigned short*)carve(64 * 3 * 512 * 2);
    unsigned short* sob    = (unsigned short*)carve(128 * 2 * 512 * 2);
    unsigned short* rinf   = (unsigned short*)carve(NRULE * 2 * 512 * 2);
    unsigned short* rof    = (unsigned short*)carve(NRULE * 4 * 512 * 2);
    float*          sel_t  = (float*)carve(NRULE * NBLK * 4);
    unsigned short* t_pad  = (unsigned short*)carve((size_t)MAXSLOT * 64 * 2);
    unsigned short* hs     = (unsigned short*)carve((size_t)MAXSLOT * 256 * 2);

    kprep_sort<<<dim3(1), dim3(1024), 0, stream>>>(rule_ids, logits, perm_p, srid_p, sel_t);
    kprep_pack<<<dim3(64), dim3(256), 0, stream>>>(shared_in, shared_out, rule_in, rule_out,
                                                   ssb, sob, rinf, rof);
    k1<<<dim3(NTILE), dim3(256), 0, stream>>>(x, perm_p, srid_p, ssb, rinf, sel_t, t_pad, hs);
    k2<<<dim3(NTILE), dim3(256), 0, stream>>>(t_pad, hs, perm_p, srid_p, sob, rof, out);
}

// Round 4
// 119.060 us; speedup vs baseline: 2.3115x; 1.3302x over previous
//
#include <hip/hip_runtime.h>
#include <hip/hip_bf16.h>
#include <math.h>

#define NTOK  16384
#define INF   2048
#define OUTF  2048
#define SR    45
#define RANK  8
#define BLK   64
#define NBLK  32
#define NRULE 256
#define MAXSLOT (NTOK + NRULE * 15)   // 20224
#define NTILE   (MAXSLOT / 16)        // 1264 blocks of 16 slots

typedef __attribute__((ext_vector_type(8))) short bf16x8;
typedef __attribute__((ext_vector_type(4))) float f32x4;

__device__ inline short f2bs(float f) {
    __hip_bfloat16 h = __float2bfloat16(f);   // RTNE; compiler packs to v_cvt_pk_bf16_f32
    return *reinterpret_cast<short*>(&h);
}
__device__ inline bf16x8 cvt8(const float4& a, const float4& b) {
    bf16x8 r;
    r[0] = f2bs(a.x); r[1] = f2bs(a.y); r[2] = f2bs(a.z); r[3] = f2bs(a.w);
    r[4] = f2bs(b.x); r[5] = f2bs(b.y); r[6] = f2bs(b.z); r[7] = f2bs(b.w);
    return r;
}

// ---------------------------------------------------------------------------
// prep A: blocks 0..127 pack weights into MFMA B-frag layout (bf16);
//         blocks 128..159 histogram rule_ids + init perm/srid.
// B-frag (16x16x32): lane l holds B[k=(l>>4)*8+j][col=l&15], j=0..7.
// ---------------------------------------------------------------------------
__global__ void kprep_a(const int* __restrict__ rule_ids,
                        const float* __restrict__ shared_in,
                        const float* __restrict__ shared_out,
                        const float* __restrict__ rule_in,
                        const float* __restrict__ rule_out,
                        unsigned short* __restrict__ ssb,   // [64ch][3nf][64][8]
                        unsigned short* __restrict__ sob,   // [128CF][2kc][64][8]
                        unsigned short* __restrict__ rinf,  // [256][2half][64][8]
                        unsigned short* __restrict__ rof,   // [256][4cf][64][8]
                        int* __restrict__ ghist,
                        int* __restrict__ perm_p,
                        int* __restrict__ srid_p)
{
    if (blockIdx.x < 128) {
        const int tid = blockIdx.x * 256 + threadIdx.x;
        const int stride = 128 * 256;
        for (int idx = tid; idx < 64 * 3 * 512; idx += stride) {
            int ch = idx / 1536, rem = idx - ch * 1536;
            int nf = rem / 512;
            int l = (rem >> 3) & 63, j = idx & 7;
            int k = ch * 32 + ((l >> 4) << 3) + j;
            int col = nf * 16 + (l & 15);
            ssb[idx] = (col < SR) ? (unsigned short)f2bs(shared_in[(size_t)k * SR + col]) : 0;
        }
        for (int idx = tid; idx < 128 * 2 * 512; idx += stride) {
            int CF = idx >> 10;
            int kc = (idx >> 9) & 1;
            int l = (idx >> 3) & 63, j = idx & 7;
            int k = kc * 32 + ((l >> 4) << 3) + j;
            int col = CF * 16 + (l & 15);
            sob[idx] = (k < SR) ? (unsigned short)f2bs(shared_out[(size_t)k * OUTF + col]) : 0;
        }
        for (int idx = tid; idx < NRULE * 2 * 512; idx += stride) {
            int rid = idx >> 10;
            int half = (idx >> 9) & 1;
            int l = (idx >> 3) & 63, j = idx & 7;
            int r = l & 15;
            int s = half * 32 + ((l >> 4) << 3) + j;
            rinf[idx] = (r < RANK) ? (unsigned short)f2bs(rule_in[(size_t)rid * 512 + s * RANK + r]) : 0;
        }
        for (int idx = tid; idx < NRULE * 4 * 512; idx += stride) {
            int rid = idx >> 11;
            int cf = (idx >> 9) & 3;
            int l = (idx >> 3) & 63, j = idx & 7;
            int k = ((l >> 4) << 3) + j;
            int c = cf * 16 + (l & 15);
            rof[idx] = (k < RANK) ? (unsigned short)f2bs(rule_out[(size_t)rid * 512 + k * BLK + c]) : 0;
        }
    } else {
        __shared__ int lh[NRULE];
        const int tid = threadIdx.x;
        const int hb = blockIdx.x - 128;          // 0..31
        lh[tid] = 0;
        __syncthreads();
        const int base = hb * 512;
        atomicAdd(&lh[rule_ids[base + tid]], 1);
        atomicAdd(&lh[rule_ids[base + 256 + tid]], 1);
        __syncthreads();
        if (lh[tid]) atomicAdd(&ghist[tid], lh[tid]);
        for (int j = tid; j < MAXSLOT / 32; j += 256) {
            int idx = hb * (MAXSLOT / 32) + j;
            perm_p[idx] = -1;
            srid_p[idx] = 0;
        }
    }
}

// ---------------------------------------------------------------------------
// prep B (1 block): scan padded hist -> cursors, pad srid, sel table, ntot.
// ---------------------------------------------------------------------------
__global__ void kprep_scan(const int* __restrict__ ghist,
                           const float* __restrict__ logits,
                           int* __restrict__ gcnt,
                           int* __restrict__ srid_p,
                           float* __restrict__ sel_t,
                           int* __restrict__ ntot)
{
    __shared__ int sc[NRULE];
    const int tid = threadIdx.x;                  // 256 threads
    const int h = ghist[tid];
    const int pd = (h + 15) & ~15;
    sc[tid] = pd;
    for (int off = 1; off < NRULE; off <<= 1) {
        __syncthreads();
        int v = (tid >= off) ? sc[tid - off] : 0;
        __syncthreads();
        sc[tid] += v;
    }
    __syncthreads();
    const int excl = sc[tid] - pd;
    gcnt[tid] = excl;
    for (int q = h; q < pd; ++q) srid_p[excl + q] = tid;   // pad slots keep perm=-1
    if (tid == NRULE - 1) *ntot = sc[tid];
    // softmax table, temp = sqrt(32)
    const float invT = 5.65685424949238f;
    const float* __restrict__ lg = logits + (size_t)tid * NBLK;
    float m = -1e30f;
    for (int b = 0; b < NBLK; ++b) m = fmaxf(m, lg[b] * invT);
    float s = 0.0f;
    for (int b = 0; b < NBLK; ++b) s += expf(lg[b] * invT - m);
    const float inv = 1.0f / s;
    for (int b = 0; b < NBLK; ++b)
        sel_t[(size_t)tid * NBLK + b] = expf(lg[b] * invT - m) * inv;
}

// ---------------------------------------------------------------------------
// prep C: scatter tokens to padded slots (order within rule is arbitrary;
// per-token output is slot-independent, so result stays deterministic).
// ---------------------------------------------------------------------------
__global__ void kprep_scatter(const int* __restrict__ rule_ids,
                              int* __restrict__ gcnt,
                              int* __restrict__ perm_p,
                              int* __restrict__ srid_p)
{
    const int i = blockIdx.x * 256 + threadIdx.x;  // 64 blocks
    const int r = rule_ids[i];
    const int p = atomicAdd(&gcnt[r], 1);
    perm_p[p] = i;
    srid_p[p] = r;
}

// ---------------------------------------------------------------------------
// kmain (fused): per 16-slot tile (rule-uniform):
//   phase 1: 4 waves = K-quarters; t partials -> tred (LDS), hidden -> hs_lds
//   reduce:  t = sum(tred) -> t_bf (LDS, bf16, padded K=64)
//   phase 2: 4 waves = col-quarters; out = t@shared_out + hs@rule_out
// ---------------------------------------------------------------------------
__global__ __launch_bounds__(256, 4)
void kmain(const float* __restrict__ x,
           const int* __restrict__ perm_p,
           const int* __restrict__ srid_p,
           const unsigned short* __restrict__ ssb,
           const unsigned short* __restrict__ sob,
           const unsigned short* __restrict__ rinf,
           const unsigned short* __restrict__ rof,
           const float* __restrict__ sel_t,
           const int* __restrict__ ntot,
           float* __restrict__ out)
{
    __shared__ __align__(16) float tred[4][16][52];          // 13.3 KB
    __shared__ __align__(16) unsigned short t_bf[16 * 72];   // 2.25 KB
    __shared__ __align__(16) unsigned short hs_lds[16 * 264];// 8.25 KB

    const int slot0 = blockIdx.x * 16;
    if (slot0 >= *ntot) return;                  // pure-pad tail tiles

    const int tid = threadIdx.x;
    const int lane = tid & 63, w = tid >> 6;     // w = K-quarter / col-quarter
    const int row_l = lane & 15, grp = lane >> 4;

    const int rid_s = srid_p[slot0];             // tile-uniform rule
    const int ptok  = perm_p[slot0 + row_l];
    const size_t prow = (size_t)(ptok < 0 ? 0 : ptok);

    const float* __restrict__ xr = x + prow * INF + w * 512 + (grp << 3);
    const unsigned short* __restrict__ ssb_w =
        ssb + ((size_t)(w * 16) * 3) * 512 + lane * 8;
    const unsigned short* __restrict__ rin_w =
        rinf + ((size_t)rid_s * 2) * 512 + lane * 8;

    f32x4 aT0 = {0.f, 0.f, 0.f, 0.f};
    f32x4 aT1 = {0.f, 0.f, 0.f, 0.f};
    f32x4 aT2 = {0.f, 0.f, 0.f, 0.f};
    f32x4 aH  = {0.f, 0.f, 0.f, 0.f};

    // ---- phase 1: x prefetch ring depth 4 (dist 3), weights double-buffered
    float4 xb[4][2];
    bf16x8 wb[2][4];
#pragma unroll
    for (int s_ = 0; s_ < 3; ++s_) {
        xb[s_][0] = *reinterpret_cast<const float4*>(xr + s_ * 32);
        xb[s_][1] = *reinterpret_cast<const float4*>(xr + s_ * 32 + 4);
    }
    wb[0][0] = *reinterpret_cast<const bf16x8*>(ssb_w);
    wb[0][1] = *reinterpret_cast<const bf16x8*>(ssb_w + 512);
    wb[0][2] = *reinterpret_cast<const bf16x8*>(ssb_w + 1024);
    wb[0][3] = *reinterpret_cast<const bf16x8*>(rin_w);

#pragma unroll
    for (int sub = 0; sub < 16; ++sub) {
        if (sub < 15) {                          // weight prefetch (L2-hot)
            const unsigned short* sp = ssb_w + (size_t)(sub + 1) * 1536;
            wb[(sub + 1) & 1][0] = *reinterpret_cast<const bf16x8*>(sp);
            wb[(sub + 1) & 1][1] = *reinterpret_cast<const bf16x8*>(sp + 512);
            wb[(sub + 1) & 1][2] = *reinterpret_cast<const bf16x8*>(sp + 1024);
            wb[(sub + 1) & 1][3] = *reinterpret_cast<const bf16x8*>(rin_w + ((sub + 1) & 1) * 512);
        }
        if (sub < 13) {                          // x prefetch (HBM, 3 ahead)
            xb[(sub + 3) & 3][0] = *reinterpret_cast<const float4*>(xr + (sub + 3) * 32);
            xb[(sub + 3) & 3][1] = *reinterpret_cast<const float4*>(xr + (sub + 3) * 32 + 4);
        }
        const bf16x8 af = cvt8(xb[sub & 3][0], xb[sub & 3][1]);
        aT0 = __builtin_amdgcn_mfma_f32_16x16x32_bf16(af, wb[sub & 1][0], aT0, 0, 0, 0);
        aT1 = __builtin_amdgcn_mfma_f32_16x16x32_bf16(af, wb[sub & 1][1], aT1, 0, 0, 0);
        aT2 = __builtin_amdgcn_mfma_f32_16x16x32_bf16(af, wb[sub & 1][2], aT2, 0, 0, 0);
        aH  = __builtin_amdgcn_mfma_f32_16x16x32_bf16(af, wb[sub & 1][3], aH, 0, 0, 0);
        if (sub & 1) {                           // one 64-col block done
            const int bb = (w << 3) + (sub >> 1);
            const float sel = sel_t[rid_s * NBLK + bb];
            if (row_l < RANK) {
#pragma unroll
                for (int q = 0; q < 4; ++q)
                    hs_lds[((grp << 2) + q) * 264 + bb * 8 + row_l] =
                        (unsigned short)f2bs(aH[q] * sel);
            }
            aH[0] = 0.f; aH[1] = 0.f; aH[2] = 0.f; aH[3] = 0.f;
        }
    }

#pragma unroll
    for (int q = 0; q < 4; ++q) {
        tred[w][(grp << 2) + q][row_l]      = aT0[q];
        tred[w][(grp << 2) + q][16 + row_l] = aT1[q];
        tred[w][(grp << 2) + q][32 + row_l] = aT2[q];
    }
    __syncthreads();
#pragma unroll
    for (int it = 0; it < 4; ++it) {             // reduce 4 K-quarters -> bf16
        const int idx = tid + it * 256;          // 16 tok x 64 cols
        const int tk = idx >> 6, c = idx & 63;
        float v = 0.f;
        if (c < 48)
            v = tred[0][tk][c] + tred[1][tk][c] + tred[2][tk][c] + tred[3][tk][c];
        t_bf[tk * 72 + c] = (unsigned short)f2bs(v);
    }
    __syncthreads();

    // ---- phase 2: wave w covers cols [w*512, w*512+512)
    const bf16x8 at0 = *reinterpret_cast<const bf16x8*>(&t_bf[row_l * 72 + (grp << 3)]);
    const bf16x8 at1 = *reinterpret_cast<const bf16x8*>(&t_bf[row_l * 72 + 32 + (grp << 3)]);
    const int4 pv = *reinterpret_cast<const int4*>(perm_p + slot0 + (grp << 2));
    const int pvq[4] = {pv.x, pv.y, pv.z, pv.w};

    const unsigned short* __restrict__ sob_w =
        sob + (size_t)(w * 32) * 1024 + lane * 8;
    const unsigned short* __restrict__ rof_w =
        rof + ((size_t)rid_s * 4) * 512 + lane * 8;

    bf16x8 ah = {0, 0, 0, 0, 0, 0, 0, 0};
#pragma unroll 4
    for (int cf = 0; cf < 32; ++cf) {
        const int CF = (w << 5) + cf;
        if ((cf & 3) == 0) {
            const int bb = CF >> 2;
            bf16x8 z = {0, 0, 0, 0, 0, 0, 0, 0};
            ah = z;
            if (lane < 16)
                ah = *reinterpret_cast<const bf16x8*>(&hs_lds[lane * 264 + bb * 8]);
        }
        const unsigned short* __restrict__ sf = sob_w + (size_t)cf * 1024;
        f32x4 acc = {0.f, 0.f, 0.f, 0.f};
        acc = __builtin_amdgcn_mfma_f32_16x16x32_bf16(
            at0, *reinterpret_cast<const bf16x8*>(sf), acc, 0, 0, 0);
        acc = __builtin_amdgcn_mfma_f32_16x16x32_bf16(
            at1, *reinterpret_cast<const bf16x8*>(sf + 512), acc, 0, 0, 0);
        acc = __builtin_amdgcn_mfma_f32_16x16x32_bf16(
            ah, *reinterpret_cast<const bf16x8*>(rof_w + (CF & 3) * 512), acc, 0, 0, 0);
        const int col = (CF << 4) + row_l;
#pragma unroll
        for (int q = 0; q < 4; ++q)
            if (pvq[q] >= 0) out[(size_t)pvq[q] * OUTF + col] = acc[q];
    }
}

extern "C" void kernel_launch(void* const* d_in, const int* in_sizes, int n_in,
                              void* d_out, int out_size, void* d_ws, size_t ws_size,
                              hipStream_t stream)
{
    const float* x          = (const float*)d_in[0];
    const int*   rule_ids   = (const int*)  d_in[1];
    const float* shared_in  = (const float*)d_in[2];
    const float* shared_out = (const float*)d_in[3];
    const float* rule_in    = (const float*)d_in[4];
    const float* rule_out   = (const float*)d_in[5];
    const float* logits     = (const float*)d_in[6];
    float* out = (float*)d_out;

    char* p = (char*)d_ws;
    auto carve = [&p](size_t bytes) {
        char* r = p;
        p += (bytes + 255) & ~(size_t)255;
        return r;
    };
    int*            perm_p = (int*)carve(MAXSLOT * 4);
    int*            srid_p = (int*)carve(MAXSLOT * 4);
    unsigned short* ssb    = (unsigned short*)carve(64 * 3 * 512 * 2);
    unsigned short* sob    = (unsigned short*)carve(128 * 2 * 512 * 2);
    unsigned short* rinf   = (unsigned short*)carve((size_t)NRULE * 2 * 512 * 2);
    unsigned short* rof    = (unsigned short*)carve((size_t)NRULE * 4 * 512 * 2);
    float*          sel_t  = (float*)carve((size_t)NRULE * NBLK * 4);
    int*            ghist  = (int*)carve(NRULE * 4);
    int*            gcnt   = (int*)carve(NRULE * 4);
    int*            ntot   = (int*)carve(4);

    hipMemsetAsync(ghist, 0, NRULE * sizeof(int), stream);
    kprep_a<<<dim3(160), dim3(256), 0, stream>>>(
        rule_ids, shared_in, shared_out, rule_in, rule_out,
        ssb, sob, rinf, rof, ghist, perm_p, srid_p);
    kprep_scan<<<dim3(1), dim3(256), 0, stream>>>(
        ghist, logits, gcnt, srid_p, sel_t, ntot);
    kprep_scatter<<<dim3(64), dim3(256), 0, stream>>>(
        rule_ids, gcnt, perm_p, srid_p);
    kmain<<<dim3(NTILE), dim3(256), 0, stream>>>(
        x, perm_p, srid_p, ssb, sob, rinf, rof, sel_t, ntot, out);
}

// Round 5
// 113.421 us; speedup vs baseline: 2.4265x; 1.0497x over previous
//
#include <hip/hip_runtime.h>
#include <hip/hip_bf16.h>
#include <math.h>

#define NTOK  16384
#define INF   2048
#define OUTF  2048
#define SR    45
#define RANK  8
#define BLK   64
#define NBLK  32
#define NRULE 256
#define MAXSLOT (NTOK + NRULE * 15)   // 20224
#define NTILE32 (MAXSLOT / 32)        // 632 blocks of 32 slots

typedef __attribute__((ext_vector_type(8))) short bf16x8;
typedef __attribute__((ext_vector_type(4))) float f32x4;

typedef const __attribute__((address_space(1))) unsigned int GU32;
typedef __attribute__((address_space(3))) unsigned int LU32;

#define MFMA __builtin_amdgcn_mfma_f32_16x16x32_bf16

#define VMCNT(n) do { asm volatile("s_waitcnt vmcnt(" #n ")" ::: "memory"); \
                      __builtin_amdgcn_sched_barrier(0); } while (0)
#define LGKM0()  do { asm volatile("s_waitcnt lgkmcnt(0)" ::: "memory"); \
                      __builtin_amdgcn_sched_barrier(0); } while (0)
#define BAR()    do { __builtin_amdgcn_sched_barrier(0); \
                      __builtin_amdgcn_s_barrier(); \
                      __builtin_amdgcn_sched_barrier(0); } while (0)

__device__ inline short f2bs(float f) {
    __hip_bfloat16 h = __float2bfloat16(f);
    return *reinterpret_cast<short*>(&h);
}
__device__ inline bf16x8 cvt8(const float4& a, const float4& b) {
    bf16x8 r;
    r[0] = f2bs(a.x); r[1] = f2bs(a.y); r[2] = f2bs(a.z); r[3] = f2bs(a.w);
    r[4] = f2bs(b.x); r[5] = f2bs(b.y); r[6] = f2bs(b.z); r[7] = f2bs(b.w);
    return r;
}

// ---------------------------------------------------------------------------
// prep A: blocks 0..127 pack weights into MFMA B-frag layout (bf16);
//         blocks 128..159 histogram rule_ids + init perm/srid.
// ---------------------------------------------------------------------------
__global__ void kprep_a(const int* __restrict__ rule_ids,
                        const float* __restrict__ shared_in,
                        const float* __restrict__ shared_out,
                        const float* __restrict__ rule_in,
                        const float* __restrict__ rule_out,
                        unsigned short* __restrict__ ssb,   // [64ch][3nf][64][8]
                        unsigned short* __restrict__ sob,   // [128CF][2kc][64][8]
                        unsigned short* __restrict__ rinf,  // [256][2half][64][8]
                        unsigned short* __restrict__ rof,   // [256][4cf][64][8]
                        int* __restrict__ ghist,
                        int* __restrict__ perm_p,
                        int* __restrict__ srid_p)
{
    if (blockIdx.x < 128) {
        const int tid = blockIdx.x * 256 + threadIdx.x;
        const int stride = 128 * 256;
        for (int idx = tid; idx < 64 * 3 * 512; idx += stride) {
            int ch = idx / 1536, rem = idx - ch * 1536;
            int nf = rem / 512;
            int l = (rem >> 3) & 63, j = idx & 7;
            int k = ch * 32 + ((l >> 4) << 3) + j;
            int col = nf * 16 + (l & 15);
            ssb[idx] = (col < SR) ? (unsigned short)f2bs(shared_in[(size_t)k * SR + col]) : 0;
        }
        for (int idx = tid; idx < 128 * 2 * 512; idx += stride) {
            int CF = idx >> 10;
            int kc = (idx >> 9) & 1;
            int l = (idx >> 3) & 63, j = idx & 7;
            int k = kc * 32 + ((l >> 4) << 3) + j;
            int col = CF * 16 + (l & 15);
            sob[idx] = (k < SR) ? (unsigned short)f2bs(shared_out[(size_t)k * OUTF + col]) : 0;
        }
        for (int idx = tid; idx < NRULE * 2 * 512; idx += stride) {
            int rid = idx >> 10;
            int half = (idx >> 9) & 1;
            int l = (idx >> 3) & 63, j = idx & 7;
            int r = l & 15;
            int s = half * 32 + ((l >> 4) << 3) + j;
            rinf[idx] = (r < RANK) ? (unsigned short)f2bs(rule_in[(size_t)rid * 512 + s * RANK + r]) : 0;
        }
        for (int idx = tid; idx < NRULE * 4 * 512; idx += stride) {
            int rid = idx >> 11;
            int cf = (idx >> 9) & 3;
            int l = (idx >> 3) & 63, j = idx & 7;
            int k = ((l >> 4) << 3) + j;
            int c = cf * 16 + (l & 15);
            rof[idx] = (k < RANK) ? (unsigned short)f2bs(rule_out[(size_t)rid * 512 + k * BLK + c]) : 0;
        }
    } else {
        __shared__ int lh[NRULE];
        const int tid = threadIdx.x;
        const int hb = blockIdx.x - 128;          // 0..31
        lh[tid] = 0;
        __syncthreads();
        const int base = hb * 512;
        atomicAdd(&lh[rule_ids[base + tid]], 1);
        atomicAdd(&lh[rule_ids[base + 256 + tid]], 1);
        __syncthreads();
        if (lh[tid]) atomicAdd(&ghist[tid], lh[tid]);
        for (int j = tid; j < MAXSLOT / 32; j += 256) {
            int idx = hb * (MAXSLOT / 32) + j;
            perm_p[idx] = -1;
            srid_p[idx] = 0;
        }
    }
}

// ---------------------------------------------------------------------------
// prep B (1 block, 256 thr): scan padded hist -> cursors, pad srid, sel, ntot
// ---------------------------------------------------------------------------
__global__ void kprep_scan(const int* __restrict__ ghist,
                           const float* __restrict__ logits,
                           int* __restrict__ gcnt,
                           int* __restrict__ srid_p,
                           float* __restrict__ sel_t,
                           int* __restrict__ ntot)
{
    __shared__ int sc[NRULE];
    const int tid = threadIdx.x;
    const int h = ghist[tid];
    const int pd = (h + 15) & ~15;
    sc[tid] = pd;
    for (int off = 1; off < NRULE; off <<= 1) {
        __syncthreads();
        int v = (tid >= off) ? sc[tid - off] : 0;
        __syncthreads();
        sc[tid] += v;
    }
    __syncthreads();
    const int excl = sc[tid] - pd;
    gcnt[tid] = excl;
    for (int q = h; q < pd; ++q) srid_p[excl + q] = tid;
    if (tid == NRULE - 1) *ntot = sc[tid];
    const float invT = 5.65685424949238f;
    const float* __restrict__ lg = logits + (size_t)tid * NBLK;
    float m = -1e30f;
    for (int b = 0; b < NBLK; ++b) m = fmaxf(m, lg[b] * invT);
    float s = 0.0f;
    for (int b = 0; b < NBLK; ++b) s += expf(lg[b] * invT - m);
    const float inv = 1.0f / s;
    for (int b = 0; b < NBLK; ++b)
        sel_t[(size_t)tid * NBLK + b] = expf(lg[b] * invT - m) * inv;
}

// ---------------------------------------------------------------------------
// prep C: scatter tokens to padded slots.
// ---------------------------------------------------------------------------
__global__ void kprep_scatter(const int* __restrict__ rule_ids,
                              int* __restrict__ gcnt,
                              int* __restrict__ perm_p,
                              int* __restrict__ srid_p)
{
    const int i = blockIdx.x * 256 + threadIdx.x;
    const int r = rule_ids[i];
    const int p = atomicAdd(&gcnt[r], 1);
    perm_p[p] = i;
    srid_p[p] = r;
}

// ---------------------------------------------------------------------------
// kmain: 32 slots (2 rule-uniform strips of 16) per block, 4 waves.
// Phase 1: waves=(strip s, K-subpair p); x -> LDS via global_load_lds DMA,
//          triple-buffered, 2 chunks (of 128 cols) in flight, vmcnt-counted.
//          x LDS is XOR-source-swizzled (16B unit ^ (row&7)) to kill the
//          16-way ds_read bank conflict; readers XOR the same mask.
// Phase 2: waves=(strip s, col-half p); sob prefetched a quad ahead.
// ---------------------------------------------------------------------------
__global__ __launch_bounds__(256, 2)
void kmain(const float* __restrict__ x,
           const int* __restrict__ perm_p,
           const int* __restrict__ srid_p,
           const unsigned short* __restrict__ ssb,
           const unsigned short* __restrict__ sob,
           const unsigned short* __restrict__ rinf,
           const unsigned short* __restrict__ rof,
           const float* __restrict__ sel_t,
           const int* __restrict__ ntot,
           float* __restrict__ dummy,
           float* __restrict__ out)
{
    __shared__ __align__(16) float xbuf[3][32][128];          // 48 KB
    __shared__ __align__(16) float tred1[2][16][52];          // 6.5 KB
    __shared__ __align__(16) unsigned short hs_lds[32 * 264]; // 16.5 KB
    __shared__ __align__(16) unsigned short t_bf[32 * 72];    // 4.5 KB

    const int slot0 = blockIdx.x * 32;
    if (slot0 >= *ntot) return;

    const int tid  = threadIdx.x;
    const int lane = tid & 63;
    const int w    = tid >> 6;
    const int s    = w & 1;          // strip
    const int p    = w >> 1;         // K-subpair (ph1) / col-half (ph2)
    const int row_l = lane & 15, grp = lane >> 4;
    const int slotbase = slot0 + s * 16;

    const int rid_v = srid_p[slotbase];
    const int rid_u = __builtin_amdgcn_readfirstlane(rid_v);

    // ---- prologue loads (drained before the counted pipeline starts) ------
    const int par = lane >> 5;        // which of 2 rows this lane stages
    const int uu  = lane & 31;        // 16B unit within row
    const char* gsrc0; const char* gsrc1; const char* gsrc2; const char* gsrc3;
    {
        const char* t[4];
#pragma unroll
        for (int j = 0; j < 4; ++j) {
            const int r = w * 8 + j * 2 + par;
            int tok = perm_p[slot0 + r];
            if (tok < 0) tok = 0;
            t[j] = (const char*)(x + (size_t)tok * INF) + ((uu ^ (r & 7)) << 4);
        }
        gsrc0 = t[0]; gsrc1 = t[1]; gsrc2 = t[2]; gsrc3 = t[3];
    }
    const bf16x8 ri0 = *(const bf16x8*)(rinf + ((size_t)rid_u * 2 + 0) * 512 + lane * 8);
    const bf16x8 ri1 = *(const bf16x8*)(rinf + ((size_t)rid_u * 2 + 1) * 512 + lane * 8);

    // ds_read byte offsets (within one x buffer) for this wave's 2 subs
    const int rphys = s * 16 + row_l;
    int offA0, offA1, offB0, offB1;
    {
        const int u0 = (2 * p + 0) * 8 + grp * 2;
        const int u1 = (2 * p + 1) * 8 + grp * 2;
        offA0 = (rphys * 32 + ((u0 + 0) ^ (rphys & 7))) << 4;
        offA1 = (rphys * 32 + ((u0 + 1) ^ (rphys & 7))) << 4;
        offB0 = (rphys * 32 + ((u1 + 0) ^ (rphys & 7))) << 4;
        offB1 = (rphys * 32 + ((u1 + 1) ^ (rphys & 7))) << 4;
    }
    const unsigned short* wptr = ssb + (size_t)(2 * p) * 3 * 512 + lane * 8;

    VMCNT(0);   // counter clean: pipeline accounting is exact from here

#define STAGE(B, C) do { \
        char* _lb = (char*)(&xbuf[(B)][0][0]) + w * 4096; \
        const size_t _co = (size_t)(C) * 512; \
        __builtin_amdgcn_global_load_lds((GU32*)(gsrc0 + _co), (LU32*)(_lb),        16, 0, 0); \
        __builtin_amdgcn_global_load_lds((GU32*)(gsrc1 + _co), (LU32*)(_lb + 1024), 16, 0, 0); \
        __builtin_amdgcn_global_load_lds((GU32*)(gsrc2 + _co), (LU32*)(_lb + 2048), 16, 0, 0); \
        __builtin_amdgcn_global_load_lds((GU32*)(gsrc3 + _co), (LU32*)(_lb + 3072), 16, 0, 0); \
    } while (0)

#define WLOAD(B, C) do { \
        const unsigned short* _wp = wptr + (size_t)(C) * 6144; \
        wb[(B)][0] = *(const bf16x8*)(_wp); \
        wb[(B)][1] = *(const bf16x8*)(_wp + 512); \
        wb[(B)][2] = *(const bf16x8*)(_wp + 1024); \
        wb[(B)][3] = *(const bf16x8*)(_wp + 1536); \
        wb[(B)][4] = *(const bf16x8*)(_wp + 2048); \
        wb[(B)][5] = *(const bf16x8*)(_wp + 2560); \
    } while (0)

    bf16x8 wb[2][6];
    f32x4 aT0 = {0.f, 0.f, 0.f, 0.f};
    f32x4 aT1 = {0.f, 0.f, 0.f, 0.f};
    f32x4 aT2 = {0.f, 0.f, 0.f, 0.f};

    STAGE(0, 0); STAGE(1, 1); WLOAD(0, 0);      // 14 VMEM outstanding

#pragma unroll
    for (int c = 0; c < 16; ++c) {
        if (c < 14) STAGE((c + 2) % 3, c + 2);
        if (c < 15) WLOAD((c + 1) & 1, c + 1);
        if (c < 14)      { VMCNT(14); }          // keep DMA(c+1,c+2)+wb(c+1)
        else if (c == 14){ VMCNT(10); }
        else             { VMCNT(0);  }
        BAR();                                   // all waves' DMA(c) landed
        {
            const char* xb = (const char*)(&xbuf[c % 3][0][0]);
            const float4 xa0 = *(const float4*)(xb + offA0);
            const float4 xa1 = *(const float4*)(xb + offA1);
            const float4 xb0 = *(const float4*)(xb + offB0);
            const float4 xb1 = *(const float4*)(xb + offB1);
            const bf16x8 a0 = cvt8(xa0, xa1);
            const bf16x8 a1 = cvt8(xb0, xb1);
            f32x4 aH = {0.f, 0.f, 0.f, 0.f};
            aT0 = MFMA(a0, wb[c & 1][0], aT0, 0, 0, 0);
            aT1 = MFMA(a0, wb[c & 1][1], aT1, 0, 0, 0);
            aT2 = MFMA(a0, wb[c & 1][2], aT2, 0, 0, 0);
            aH  = MFMA(a0, ri0, aH, 0, 0, 0);
            aT0 = MFMA(a1, wb[c & 1][3], aT0, 0, 0, 0);
            aT1 = MFMA(a1, wb[c & 1][4], aT1, 0, 0, 0);
            aT2 = MFMA(a1, wb[c & 1][5], aT2, 0, 0, 0);
            aH  = MFMA(a1, ri1, aH, 0, 0, 0);
            const int b = 2 * c + p;
            const float sel = sel_t[(size_t)rid_u * NBLK + b];   // scalar path
            if (row_l < RANK) {
                const int hbase = (s * 16 + (grp << 2)) * 264 + b * 8 + row_l;
                hs_lds[hbase]       = (unsigned short)f2bs(aH[0] * sel);
                hs_lds[hbase + 264] = (unsigned short)f2bs(aH[1] * sel);
                hs_lds[hbase + 528] = (unsigned short)f2bs(aH[2] * sel);
                hs_lds[hbase + 792] = (unsigned short)f2bs(aH[3] * sel);
            }
        }
        BAR();                                   // readers done before re-DMA
    }

    // ---- t reduction across the two K-subpair waves -----------------------
    if (p == 1) {
#pragma unroll
        for (int q = 0; q < 4; ++q) {
            const int tk = (grp << 2) + q;
            tred1[s][tk][row_l]      = aT0[q];
            tred1[s][tk][16 + row_l] = aT1[q];
            tred1[s][tk][32 + row_l] = aT2[q];
            t_bf[(s * 16 + tk) * 72 + 48 + row_l] = 0;   // zero K-pad 48..63
        }
    }
    LGKM0();
    BAR();
    if (p == 0) {
#pragma unroll
        for (int q = 0; q < 4; ++q) {
            const int tk = (grp << 2) + q;
            const float v0 = aT0[q] + tred1[s][tk][row_l];
            const float v1 = aT1[q] + tred1[s][tk][16 + row_l];
            const float v2 = aT2[q] + tred1[s][tk][32 + row_l];
            t_bf[(s * 16 + tk) * 72 + row_l]      = (unsigned short)f2bs(v0);
            t_bf[(s * 16 + tk) * 72 + 16 + row_l] = (unsigned short)f2bs(v1);
            t_bf[(s * 16 + tk) * 72 + 32 + row_l] = (unsigned short)f2bs(v2);
        }
    }
    LGKM0();
    BAR();

    // ---- phase 2: wave (s, col-half p) ------------------------------------
    const bf16x8 at0 = *(const bf16x8*)(&t_bf[(s * 16 + row_l) * 72 + (grp << 3)]);
    const bf16x8 at1 = *(const bf16x8*)(&t_bf[(s * 16 + row_l) * 72 + 32 + (grp << 3)]);

    const int4 pv = *(const int4*)(perm_p + slotbase + (grp << 2));
    float* const orow0 = (pv.x < 0) ? dummy : out + (size_t)pv.x * OUTF;
    float* const orow1 = (pv.y < 0) ? dummy : out + (size_t)pv.y * OUTF;
    float* const orow2 = (pv.z < 0) ? dummy : out + (size_t)pv.z * OUTF;
    float* const orow3 = (pv.w < 0) ? dummy : out + (size_t)pv.w * OUTF;

    bf16x8 rfv[4];
#pragma unroll
    for (int i = 0; i < 4; ++i)
        rfv[i] = *(const bf16x8*)(rof + ((size_t)rid_u * 4 + i) * 512 + lane * 8);
    const unsigned short* sobw = sob + (size_t)(p * 64 * 2) * 512 + lane * 8;
    VMCNT(0);

#define PLOAD(ARR, QD) do { \
        _Pragma("unroll") \
        for (int _i = 0; _i < 8; ++_i) \
            ARR[_i] = *(const bf16x8*)(sobw + ((size_t)(QD) * 8 + _i) * 512); \
    } while (0)

#define QUADC(ARR, QD) do { \
        const int _bb = p * 16 + (QD); \
        bf16x8 ah = {0, 0, 0, 0, 0, 0, 0, 0}; \
        if (lane < 16) ah = *(const bf16x8*)(&hs_lds[(s * 16 + lane) * 264 + _bb * 8]); \
        _Pragma("unroll") \
        for (int _cf = 0; _cf < 4; ++_cf) { \
            f32x4 acc = {0.f, 0.f, 0.f, 0.f}; \
            acc = MFMA(at0, ARR[_cf * 2],     acc, 0, 0, 0); \
            acc = MFMA(at1, ARR[_cf * 2 + 1], acc, 0, 0, 0); \
            acc = MFMA(ah,  rfv[_cf],         acc, 0, 0, 0); \
            const int col = ((p * 64 + (QD) * 4 + _cf) << 4) + row_l; \
            orow0[col] = acc[0]; orow1[col] = acc[1]; \
            orow2[col] = acc[2]; orow3[col] = acc[3]; \
        } \
    } while (0)

    bf16x8 sr0[8], sr1[8];
    PLOAD(sr0, 0);
#pragma unroll 1
    for (int qq = 0; qq < 7; ++qq) {
        const int q0 = qq * 2;
        PLOAD(sr1, q0 + 1); VMCNT(24); QUADC(sr0, q0);
        PLOAD(sr0, q0 + 2); VMCNT(24); QUADC(sr1, q0 + 1);
    }
    PLOAD(sr1, 15); VMCNT(24); QUADC(sr0, 14);
    VMCNT(16); QUADC(sr1, 15);
}

extern "C" void kernel_launch(void* const* d_in, const int* in_sizes, int n_in,
                              void* d_out, int out_size, void* d_ws, size_t ws_size,
                              hipStream_t stream)
{
    const float* x          = (const float*)d_in[0];
    const int*   rule_ids   = (const int*)  d_in[1];
    const float* shared_in  = (const float*)d_in[2];
    const float* shared_out = (const float*)d_in[3];
    const float* rule_in    = (const float*)d_in[4];
    const float* rule_out   = (const float*)d_in[5];
    const float* logits     = (const float*)d_in[6];
    float* out = (float*)d_out;

    char* p = (char*)d_ws;
    auto carve = [&p](size_t bytes) {
        char* r = p;
        p += (bytes + 255) & ~(size_t)255;
        return r;
    };
    int*            perm_p = (int*)carve(MAXSLOT * 4);
    int*            srid_p = (int*)carve(MAXSLOT * 4);
    unsigned short* ssb    = (unsigned short*)carve(64 * 3 * 512 * 2);
    unsigned short* sob    = (unsigned short*)carve(128 * 2 * 512 * 2);
    unsigned short* rinf   = (unsigned short*)carve((size_t)NRULE * 2 * 512 * 2);
    unsigned short* rof    = (unsigned short*)carve((size_t)NRULE * 4 * 512 * 2);
    float*          sel_t  = (float*)carve((size_t)NRULE * NBLK * 4);
    int*            ghist  = (int*)carve(NRULE * 4);
    int*            gcnt   = (int*)carve(NRULE * 4);
    int*            ntot   = (int*)carve(4);
    float*          dummy  = (float*)carve((size_t)OUTF * 4);

    hipMemsetAsync(ghist, 0, NRULE * sizeof(int), stream);
    kprep_a<<<dim3(160), dim3(256), 0, stream>>>(
        rule_ids, shared_in, shared_out, rule_in, rule_out,
        ssb, sob, rinf, rof, ghist, perm_p, srid_p);
    kprep_scan<<<dim3(1), dim3(256), 0, stream>>>(
        ghist, logits, gcnt, srid_p, sel_t, ntot);
    kprep_scatter<<<dim3(64), dim3(256), 0, stream>>>(
        rule_ids, gcnt, perm_p, srid_p);
    kmain<<<dim3(NTILE32), dim3(256), 0, stream>>>(
        x, perm_p, srid_p, ssb, sob, rinf, rof, sel_t, ntot, dummy, out);
}

// Round 6
// 110.829 us; speedup vs baseline: 2.4832x; 1.0234x over previous
//
#include <hip/hip_runtime.h>
#include <hip/hip_bf16.h>
#include <math.h>

#define NTOK  16384
#define INF   2048
#define OUTF  2048
#define SR    45
#define RANK  8
#define BLK   64
#define NBLK  32
#define NRULE 256
#define MAXSLOT (NTOK + NRULE * 15)   // 20224
#define NTILE16 (MAXSLOT / 16)        // 1264 strips of 16 slots
#define NTILE32 (MAXSLOT / 32)        // 632 tiles of 32 slots

typedef __attribute__((ext_vector_type(8))) short bf16x8;
typedef __attribute__((ext_vector_type(4))) float f32x4;
typedef __attribute__((ext_vector_type(4))) short s16x4;

#define MFMA __builtin_amdgcn_mfma_f32_16x16x32_bf16
#define SBAR() __builtin_amdgcn_sched_barrier(0)

__device__ inline short f2bs(float f) {
    __hip_bfloat16 h = __float2bfloat16(f);
    return *reinterpret_cast<short*>(&h);
}
__device__ inline bf16x8 cvt8(const float4& a, const float4& b) {
    bf16x8 r;
    r[0] = f2bs(a.x); r[1] = f2bs(a.y); r[2] = f2bs(a.z); r[3] = f2bs(a.w);
    r[4] = f2bs(b.x); r[5] = f2bs(b.y); r[6] = f2bs(b.z); r[7] = f2bs(b.w);
    return r;
}

// ---------------------------------------------------------------------------
// prep A: blocks 0..127 pack weights into MFMA B-frag layout (bf16);
//         blocks 128..159 histogram rule_ids + init perm/srid.
// B-frag (16x16x32): lane l holds B[k=(l>>4)*8+j][col=l&15], j=0..7.
// ---------------------------------------------------------------------------
__global__ void kprep_a(const int* __restrict__ rule_ids,
                        const float* __restrict__ shared_in,
                        const float* __restrict__ shared_out,
                        const float* __restrict__ rule_in,
                        const float* __restrict__ rule_out,
                        unsigned short* __restrict__ ssb,   // [64ch][3nf][64][8]
                        unsigned short* __restrict__ sob,   // [128CF][2kc][64][8]
                        unsigned short* __restrict__ rinf,  // [256][2half][64][8]
                        unsigned short* __restrict__ rof,   // [256][4cf][64][8]
                        int* __restrict__ ghist,
                        int* __restrict__ perm_p,
                        int* __restrict__ srid_p)
{
    if (blockIdx.x < 128) {
        const int tid = blockIdx.x * 256 + threadIdx.x;
        const int stride = 128 * 256;
        for (int idx = tid; idx < 64 * 3 * 512; idx += stride) {
            int ch = idx / 1536, rem = idx - ch * 1536;
            int nf = rem / 512;
            int l = (rem >> 3) & 63, j = idx & 7;
            int k = ch * 32 + ((l >> 4) << 3) + j;
            int col = nf * 16 + (l & 15);
            ssb[idx] = (col < SR) ? (unsigned short)f2bs(shared_in[(size_t)k * SR + col]) : 0;
        }
        for (int idx = tid; idx < 128 * 2 * 512; idx += stride) {
            int CF = idx >> 10;
            int kc = (idx >> 9) & 1;
            int l = (idx >> 3) & 63, j = idx & 7;
            int k = kc * 32 + ((l >> 4) << 3) + j;
            int col = CF * 16 + (l & 15);
            sob[idx] = (k < SR) ? (unsigned short)f2bs(shared_out[(size_t)k * OUTF + col]) : 0;
        }
        for (int idx = tid; idx < NRULE * 2 * 512; idx += stride) {
            int rid = idx >> 10;
            int half = (idx >> 9) & 1;
            int l = (idx >> 3) & 63, j = idx & 7;
            int r = l & 15;
            int s = half * 32 + ((l >> 4) << 3) + j;
            rinf[idx] = (r < RANK) ? (unsigned short)f2bs(rule_in[(size_t)rid * 512 + s * RANK + r]) : 0;
        }
        for (int idx = tid; idx < NRULE * 4 * 512; idx += stride) {
            int rid = idx >> 11;
            int cf = (idx >> 9) & 3;
            int l = (idx >> 3) & 63, j = idx & 7;
            int k = ((l >> 4) << 3) + j;
            int c = cf * 16 + (l & 15);
            rof[idx] = (k < RANK) ? (unsigned short)f2bs(rule_out[(size_t)rid * 512 + k * BLK + c]) : 0;
        }
    } else {
        __shared__ int lh[NRULE];
        const int tid = threadIdx.x;
        const int hb = blockIdx.x - 128;          // 0..31
        lh[tid] = 0;
        __syncthreads();
        const int base = hb * 512;
        atomicAdd(&lh[rule_ids[base + tid]], 1);
        atomicAdd(&lh[rule_ids[base + 256 + tid]], 1);
        __syncthreads();
        if (lh[tid]) atomicAdd(&ghist[tid], lh[tid]);
        for (int j = tid; j < MAXSLOT / 32; j += 256) {
            int idx = hb * (MAXSLOT / 32) + j;
            perm_p[idx] = -1;
            srid_p[idx] = 0;
        }
    }
}

// ---------------------------------------------------------------------------
// prep B (1 block, 256 thr): scan padded hist -> cursors, pad srid, sel, ntot
// ---------------------------------------------------------------------------
__global__ void kprep_scan(const int* __restrict__ ghist,
                           const float* __restrict__ logits,
                           int* __restrict__ gcnt,
                           int* __restrict__ srid_p,
                           float* __restrict__ sel_t,
                           int* __restrict__ ntot)
{
    __shared__ int sc[NRULE];
    const int tid = threadIdx.x;
    const int h = ghist[tid];
    const int pd = (h + 15) & ~15;
    sc[tid] = pd;
    for (int off = 1; off < NRULE; off <<= 1) {
        __syncthreads();
        int v = (tid >= off) ? sc[tid - off] : 0;
        __syncthreads();
        sc[tid] += v;
    }
    __syncthreads();
    const int excl = sc[tid] - pd;
    gcnt[tid] = excl;
    for (int q = h; q < pd; ++q) srid_p[excl + q] = tid;
    if (tid == NRULE - 1) *ntot = sc[tid];
    const float invT = 5.65685424949238f;
    const float* __restrict__ lg = logits + (size_t)tid * NBLK;
    float m = -1e30f;
    for (int b = 0; b < NBLK; ++b) m = fmaxf(m, lg[b] * invT);
    float s = 0.0f;
    for (int b = 0; b < NBLK; ++b) s += expf(lg[b] * invT - m);
    const float inv = 1.0f / s;
    for (int b = 0; b < NBLK; ++b)
        sel_t[(size_t)tid * NBLK + b] = expf(lg[b] * invT - m) * inv;
}

// ---------------------------------------------------------------------------
// prep C: scatter tokens to padded slots.
// ---------------------------------------------------------------------------
__global__ void kprep_scatter(const int* __restrict__ rule_ids,
                              int* __restrict__ gcnt,
                              int* __restrict__ perm_p,
                              int* __restrict__ srid_p)
{
    const int i = blockIdx.x * 256 + threadIdx.x;
    const int r = rule_ids[i];
    const int p = atomicAdd(&gcnt[r], 1);
    perm_p[p] = i;
    srid_p[p] = r;
}

// ---------------------------------------------------------------------------
// k1: one 16-slot rule-uniform strip per block; wave w = K-quarter [512w,512w+512).
// x read straight from global (no LDS, no barriers in the hot loop); register
// prefetch 3 steps ahead, issue order pinned with sched_barrier(0).
// Outputs: t_bf[slot][64] bf16 (k-padded), hs[slot][32][8] bf16 (sel-scaled).
// ---------------------------------------------------------------------------
__global__ __launch_bounds__(256, 3)
void k1(const float* __restrict__ x,
        const int* __restrict__ perm_p,
        const int* __restrict__ srid_p,
        const unsigned short* __restrict__ ssb,
        const unsigned short* __restrict__ rinf,
        const float* __restrict__ sel_t,
        const int* __restrict__ ntot,
        unsigned short* __restrict__ t_bf,
        unsigned short* __restrict__ hs)
{
    __shared__ __align__(16) float tred[4][16][52];            // 13.3 KB
    __shared__ __align__(16) unsigned short hs_lds[16 * 264];  // 8.45 KB

    const int slot0 = blockIdx.x * 16;
    if (slot0 >= *ntot) return;

    const int tid  = threadIdx.x;
    const int lane = tid & 63;
    const int w    = tid >> 6;            // K-quarter
    const int row_l = lane & 15, grp = lane >> 4;

    const int rid_u = __builtin_amdgcn_readfirstlane(srid_p[slot0]);
    int tok = perm_p[slot0 + row_l];
    if (tok < 0) tok = 0;

    const float* __restrict__ xr = x + (size_t)tok * INF + w * 512 + (grp << 3);
    const unsigned short* __restrict__ sbase =
        ssb + (size_t)(w * 16) * 1536 + lane * 8;
    const bf16x8 ri0 = *(const bf16x8*)(rinf + ((size_t)rid_u * 2 + 0) * 512 + lane * 8);
    const bf16x8 ri1 = *(const bf16x8*)(rinf + ((size_t)rid_u * 2 + 1) * 512 + lane * 8);

    f32x4 aT0 = {0.f, 0.f, 0.f, 0.f};
    f32x4 aT1 = {0.f, 0.f, 0.f, 0.f};
    f32x4 aT2 = {0.f, 0.f, 0.f, 0.f};
    f32x4 aH  = {0.f, 0.f, 0.f, 0.f};

    float4 xa[4][2];
    bf16x8 wr[2][3];
#pragma unroll
    for (int s_ = 0; s_ < 3; ++s_) {
        xa[s_][0] = *(const float4*)(xr + s_ * 32);
        xa[s_][1] = *(const float4*)(xr + s_ * 32 + 4);
    }
    wr[0][0] = *(const bf16x8*)(sbase);
    wr[0][1] = *(const bf16x8*)(sbase + 512);
    wr[0][2] = *(const bf16x8*)(sbase + 1024);
    SBAR();

#pragma unroll
    for (int c = 0; c < 16; ++c) {
        if (c < 13) {                      // x prefetch, 3 steps ahead
            xa[(c + 3) & 3][0] = *(const float4*)(xr + (c + 3) * 32);
            xa[(c + 3) & 3][1] = *(const float4*)(xr + (c + 3) * 32 + 4);
        }
        if (c < 15) {                      // weights, double-buffered (L2-hot)
            const unsigned short* sp = sbase + (size_t)(c + 1) * 1536;
            wr[(c + 1) & 1][0] = *(const bf16x8*)(sp);
            wr[(c + 1) & 1][1] = *(const bf16x8*)(sp + 512);
            wr[(c + 1) & 1][2] = *(const bf16x8*)(sp + 1024);
        }
        SBAR();                            // pin issue order: loads before compute
        const bf16x8 af = cvt8(xa[c & 3][0], xa[c & 3][1]);
        aT0 = MFMA(af, wr[c & 1][0], aT0, 0, 0, 0);
        aT1 = MFMA(af, wr[c & 1][1], aT1, 0, 0, 0);
        aT2 = MFMA(af, wr[c & 1][2], aT2, 0, 0, 0);
        aH  = MFMA(af, (c & 1) ? ri1 : ri0, aH, 0, 0, 0);
        if (c & 1) {                       // one 64-col block finished
            const int b = w * 8 + (c >> 1);
            const float sel = sel_t[(size_t)rid_u * NBLK + b];
            if (row_l < RANK) {
#pragma unroll
                for (int q = 0; q < 4; ++q)
                    hs_lds[((grp << 2) + q) * 264 + b * 8 + row_l] =
                        (unsigned short)f2bs(aH[q] * sel);
            }
            aH[0] = 0.f; aH[1] = 0.f; aH[2] = 0.f; aH[3] = 0.f;
        }
        SBAR();
    }

    // t partials -> LDS, reduce across 4 K-quarter waves, store bf16 (pad to 64)
#pragma unroll
    for (int q = 0; q < 4; ++q) {
        const int sl = (grp << 2) + q;
        tred[w][sl][row_l]      = aT0[q];
        tred[w][sl][16 + row_l] = aT1[q];
        tred[w][sl][32 + row_l] = aT2[q];
    }
    __syncthreads();
    {
        const int sl = tid >> 4;           // 0..15
        const int c0 = (tid & 15) << 2;    // 0..60, step 4
        s16x4 v = {0, 0, 0, 0};
        if (c0 < 48) {
#pragma unroll
            for (int j = 0; j < 4; ++j) {
                const float s = tred[0][sl][c0 + j] + tred[1][sl][c0 + j]
                              + tred[2][sl][c0 + j] + tred[3][sl][c0 + j];
                v[j] = f2bs(s);
            }
        }
        *(s16x4*)(t_bf + ((size_t)(slot0 + sl)) * 64 + c0) = v;
    }
    // dump sel-scaled hidden: 16 slots x 256 shorts, coalesced 16B
#pragma unroll
    for (int u = 0; u < 2; ++u) {
        const int f = tid + (u << 8);      // 0..511
        const int sl = f >> 5, j8 = f & 31;
        *(bf16x8*)(hs + ((size_t)(slot0 + sl)) * 256 + j8 * 8) =
            *(const bf16x8*)(&hs_lds[sl * 264 + j8 * 8]);
    }
}

// ---------------------------------------------------------------------------
// k2: out[perm] = t@shared_out + hs@rule_out. Zero LDS; grid = 632 x 4 col-
// quarters; wave (strip s, col-half p) covers 16 slots x 256 cols (4 blocks).
// sob/hs double-buffered one 64-col block ahead.
// ---------------------------------------------------------------------------
__global__ __launch_bounds__(256, 3)
void k2(const unsigned short* __restrict__ t_bf,
        const unsigned short* __restrict__ hs,
        const int* __restrict__ perm_p,
        const int* __restrict__ srid_p,
        const unsigned short* __restrict__ sob,
        const unsigned short* __restrict__ rof,
        const int* __restrict__ ntot,
        float* __restrict__ dummy,
        float* __restrict__ out)
{
    const int bid  = blockIdx.x;
    const int tile = bid >> 2, cq = bid & 3;
    const int slot0 = tile * 32;
    if (slot0 >= *ntot) return;

    const int tid  = threadIdx.x;
    const int lane = tid & 63;
    const int w    = tid >> 6;
    const int s    = w & 1;                // strip
    const int p    = w >> 1;               // col-half within quarter
    const int row_l = lane & 15, grp = lane >> 4;
    const int slotbase = slot0 + s * 16;

    const int rid_u = __builtin_amdgcn_readfirstlane(srid_p[slotbase]);

    const unsigned short* __restrict__ tb =
        t_bf + ((size_t)(slotbase + row_l)) * 64 + (grp << 3);
    const bf16x8 at0 = *(const bf16x8*)(tb);
    const bf16x8 at1 = *(const bf16x8*)(tb + 32);

    bf16x8 rfv[4];
#pragma unroll
    for (int i = 0; i < 4; ++i)
        rfv[i] = *(const bf16x8*)(rof + ((size_t)rid_u * 4 + i) * 512 + lane * 8);

    const int4 pv = *(const int4*)(perm_p + slotbase + (grp << 2));
    float* const orow0 = (pv.x < 0) ? dummy : out + (size_t)pv.x * OUTF;
    float* const orow1 = (pv.y < 0) ? dummy : out + (size_t)pv.y * OUTF;
    float* const orow2 = (pv.z < 0) ? dummy : out + (size_t)pv.z * OUTF;
    float* const orow3 = (pv.w < 0) ? dummy : out + (size_t)pv.w * OUTF;

    const int bb0 = cq * 8 + p * 4;        // first 64-col block of this wave

    bf16x8 sb[2][8];
    bf16x8 ah[2];

#define LOADB(BUF, BI) do { \
        const int _bb = bb0 + (BI); \
        bf16x8 _z = {0, 0, 0, 0, 0, 0, 0, 0}; \
        ah[BUF] = _z; \
        if (lane < 16) \
            ah[BUF] = *(const bf16x8*)(hs + ((size_t)(slotbase + lane)) * 256 + _bb * 8); \
        const unsigned short* _sp = sob + ((size_t)_bb * 4) * 1024 + lane * 8; \
        _Pragma("unroll") \
        for (int _cf = 0; _cf < 4; ++_cf) { \
            sb[BUF][_cf * 2]     = *(const bf16x8*)(_sp + _cf * 1024); \
            sb[BUF][_cf * 2 + 1] = *(const bf16x8*)(_sp + _cf * 1024 + 512); \
        } \
    } while (0)

    LOADB(0, 0);
    SBAR();
#pragma unroll
    for (int bi = 0; bi < 4; ++bi) {
        if (bi < 3) LOADB((bi + 1) & 1, bi + 1);
        SBAR();
        const int bb = bb0 + bi;
#pragma unroll
        for (int cf = 0; cf < 4; ++cf) {
            f32x4 acc = {0.f, 0.f, 0.f, 0.f};
            acc = MFMA(at0, sb[bi & 1][cf * 2],     acc, 0, 0, 0);
            acc = MFMA(at1, sb[bi & 1][cf * 2 + 1], acc, 0, 0, 0);
            acc = MFMA(ah[bi & 1], rfv[cf],         acc, 0, 0, 0);
            const int col = ((bb * 4 + cf) << 4) + row_l;
            orow0[col] = acc[0];
            orow1[col] = acc[1];
            orow2[col] = acc[2];
            orow3[col] = acc[3];
        }
        SBAR();
    }
#undef LOADB
}

extern "C" void kernel_launch(void* const* d_in, const int* in_sizes, int n_in,
                              void* d_out, int out_size, void* d_ws, size_t ws_size,
                              hipStream_t stream)
{
    const float* x          = (const float*)d_in[0];
    const int*   rule_ids   = (const int*)  d_in[1];
    const float* shared_in  = (const float*)d_in[2];
    const float* shared_out = (const float*)d_in[3];
    const float* rule_in    = (const float*)d_in[4];
    const float* rule_out   = (const float*)d_in[5];
    const float* logits     = (const float*)d_in[6];
    float* out = (float*)d_out;

    char* p = (char*)d_ws;
    auto carve = [&p](size_t bytes) {
        char* r = p;
        p += (bytes + 255) & ~(size_t)255;
        return r;
    };
    int*            perm_p = (int*)carve(MAXSLOT * 4);
    int*            srid_p = (int*)carve(MAXSLOT * 4);
    unsigned short* ssb    = (unsigned short*)carve(64 * 3 * 512 * 2);
    unsigned short* sob    = (unsigned short*)carve(128 * 2 * 512 * 2);
    unsigned short* rinf   = (unsigned short*)carve((size_t)NRULE * 2 * 512 * 2);
    unsigned short* rof    = (unsigned short*)carve((size_t)NRULE * 4 * 512 * 2);
    float*          sel_t  = (float*)carve((size_t)NRULE * NBLK * 4);
    int*            ghist  = (int*)carve(NRULE * 4);
    int*            gcnt   = (int*)carve(NRULE * 4);
    int*            ntot   = (int*)carve(4);
    float*          dummy  = (float*)carve((size_t)OUTF * 4);
    unsigned short* t_bf   = (unsigned short*)carve((size_t)MAXSLOT * 64 * 2);
    unsigned short* hs     = (unsigned short*)carve((size_t)MAXSLOT * 256 * 2);

    hipMemsetAsync(ghist, 0, NRULE * sizeof(int), stream);
    kprep_a<<<dim3(160), dim3(256), 0, stream>>>(
        rule_ids, shared_in, shared_out, rule_in, rule_out,
        ssb, sob, rinf, rof, ghist, perm_p, srid_p);
    kprep_scan<<<dim3(1), dim3(256), 0, stream>>>(
        ghist, logits, gcnt, srid_p, sel_t, ntot);
    kprep_scatter<<<dim3(64), dim3(256), 0, stream>>>(
        rule_ids, gcnt, perm_p, srid_p);
    k1<<<dim3(NTILE16), dim3(256), 0, stream>>>(
        x, perm_p, srid_p, ssb, rinf, sel_t, ntot, t_bf, hs);
    k2<<<dim3(NTILE32 * 4), dim3(256), 0, stream>>>(
        t_bf, hs, perm_p, srid_p, sob, rof, ntot, dummy, out);
}

// Round 7
// 106.281 us; speedup vs baseline: 2.5895x; 1.0428x over previous
//
#include <hip/hip_runtime.h>
#include <hip/hip_bf16.h>
#include <math.h>

#define NTOK  16384
#define INF   2048
#define OUTF  2048
#define SR    45
#define RANK  8
#define BLK   64
#define NBLK  32
#define NRULE 256
#define NHIST 32
#define MAXSLOT (NTOK + NRULE * 15)   // 20224
#define NTILE16 (MAXSLOT / 16)        // 1264 strips of 16 slots
#define NTILE32 (MAXSLOT / 32)        // 632 tiles of 32 slots

typedef __attribute__((ext_vector_type(8))) short bf16x8;
typedef __attribute__((ext_vector_type(4))) float f32x4;
typedef __attribute__((ext_vector_type(4))) short s16x4;

#define MFMA __builtin_amdgcn_mfma_f32_16x16x32_bf16
#define SBAR() __builtin_amdgcn_sched_barrier(0)

__device__ inline short f2bs(float f) {
    __hip_bfloat16 h = __float2bfloat16(f);
    return *reinterpret_cast<short*>(&h);
}
__device__ inline bf16x8 cvt8(const float4& a, const float4& b) {
    bf16x8 r;
    r[0] = f2bs(a.x); r[1] = f2bs(a.y); r[2] = f2bs(a.z); r[3] = f2bs(a.w);
    r[4] = f2bs(b.x); r[5] = f2bs(b.y); r[6] = f2bs(b.z); r[7] = f2bs(b.w);
    return r;
}

// ---------------------------------------------------------------------------
// prep A: blocks 0..127 pack weights into MFMA B-frag layout (bf16);
//         blocks 128..159 per-block histogram (no global memset needed)
//         + init perm/srid.
// B-frag (16x16x32): lane l holds B[k=(l>>4)*8+j][col=l&15], j=0..7.
// ---------------------------------------------------------------------------
__global__ void kprep_a(const int* __restrict__ rule_ids,
                        const float* __restrict__ shared_in,
                        const float* __restrict__ shared_out,
                        const float* __restrict__ rule_in,
                        const float* __restrict__ rule_out,
                        unsigned short* __restrict__ ssb,   // [64ch][3nf][64][8]
                        unsigned short* __restrict__ sob,   // [128CF][2kc][64][8]
                        unsigned short* __restrict__ rinf,  // [256][2half][64][8]
                        unsigned short* __restrict__ rof,   // [256][4cf][64][8]
                        int* __restrict__ ghist_part,       // [32][256]
                        int* __restrict__ perm_p,
                        int* __restrict__ srid_p)
{
    if (blockIdx.x < 128) {
        const int tid = blockIdx.x * 256 + threadIdx.x;
        const int stride = 128 * 256;
        for (int idx = tid; idx < 64 * 3 * 512; idx += stride) {
            int ch = idx / 1536, rem = idx - ch * 1536;
            int nf = rem / 512;
            int l = (rem >> 3) & 63, j = idx & 7;
            int k = ch * 32 + ((l >> 4) << 3) + j;
            int col = nf * 16 + (l & 15);
            ssb[idx] = (col < SR) ? (unsigned short)f2bs(shared_in[(size_t)k * SR + col]) : 0;
        }
        for (int idx = tid; idx < 128 * 2 * 512; idx += stride) {
            int CF = idx >> 10;
            int kc = (idx >> 9) & 1;
            int l = (idx >> 3) & 63, j = idx & 7;
            int k = kc * 32 + ((l >> 4) << 3) + j;
            int col = CF * 16 + (l & 15);
            sob[idx] = (k < SR) ? (unsigned short)f2bs(shared_out[(size_t)k * OUTF + col]) : 0;
        }
        for (int idx = tid; idx < NRULE * 2 * 512; idx += stride) {
            int rid = idx >> 10;
            int half = (idx >> 9) & 1;
            int l = (idx >> 3) & 63, j = idx & 7;
            int r = l & 15;
            int s = half * 32 + ((l >> 4) << 3) + j;
            rinf[idx] = (r < RANK) ? (unsigned short)f2bs(rule_in[(size_t)rid * 512 + s * RANK + r]) : 0;
        }
        for (int idx = tid; idx < NRULE * 4 * 512; idx += stride) {
            int rid = idx >> 11;
            int cf = (idx >> 9) & 3;
            int l = (idx >> 3) & 63, j = idx & 7;
            int k = ((l >> 4) << 3) + j;
            int c = cf * 16 + (l & 15);
            rof[idx] = (k < RANK) ? (unsigned short)f2bs(rule_out[(size_t)rid * 512 + k * BLK + c]) : 0;
        }
    } else {
        __shared__ int lh[NRULE];
        const int tid = threadIdx.x;
        const int hb = blockIdx.x - 128;          // 0..31
        lh[tid] = 0;
        __syncthreads();
        const int base = hb * 512;
        atomicAdd(&lh[rule_ids[base + tid]], 1);
        atomicAdd(&lh[rule_ids[base + 256 + tid]], 1);
        __syncthreads();
        ghist_part[hb * NRULE + tid] = lh[tid];   // plain store, no memset dep
        for (int j = tid; j < MAXSLOT / 32; j += 256) {
            int idx = hb * (MAXSLOT / 32) + j;
            perm_p[idx] = -1;
            srid_p[idx] = 0;
        }
    }
}

// ---------------------------------------------------------------------------
// prep B (1 block, 256 thr): sum hist slabs, scan, pad srid, sel, ntot
// ---------------------------------------------------------------------------
__global__ void kprep_scan(const int* __restrict__ ghist_part,
                           const float* __restrict__ logits,
                           int* __restrict__ gcnt,
                           int* __restrict__ srid_p,
                           float* __restrict__ sel_t,
                           int* __restrict__ ntot)
{
    __shared__ int sc[NRULE];
    const int tid = threadIdx.x;
    int h = 0;
#pragma unroll
    for (int b = 0; b < NHIST; ++b) h += ghist_part[b * NRULE + tid];
    const int pd = (h + 15) & ~15;
    sc[tid] = pd;
    for (int off = 1; off < NRULE; off <<= 1) {
        __syncthreads();
        int v = (tid >= off) ? sc[tid - off] : 0;
        __syncthreads();
        sc[tid] += v;
    }
    __syncthreads();
    const int excl = sc[tid] - pd;
    gcnt[tid] = excl;
    for (int q = h; q < pd; ++q) srid_p[excl + q] = tid;
    if (tid == NRULE - 1) *ntot = sc[tid];
    const float invT = 5.65685424949238f;
    const float* __restrict__ lg = logits + (size_t)tid * NBLK;
    float m = -1e30f;
    for (int b = 0; b < NBLK; ++b) m = fmaxf(m, lg[b] * invT);
    float s = 0.0f;
    for (int b = 0; b < NBLK; ++b) s += expf(lg[b] * invT - m);
    const float inv = 1.0f / s;
    for (int b = 0; b < NBLK; ++b)
        sel_t[(size_t)tid * NBLK + b] = expf(lg[b] * invT - m) * inv;
}

// ---------------------------------------------------------------------------
// prep C: scatter tokens to padded slots.
// ---------------------------------------------------------------------------
__global__ void kprep_scatter(const int* __restrict__ rule_ids,
                              int* __restrict__ gcnt,
                              int* __restrict__ perm_p,
                              int* __restrict__ srid_p)
{
    const int i = blockIdx.x * 256 + threadIdx.x;
    const int r = rule_ids[i];
    const int p = atomicAdd(&gcnt[r], 1);
    perm_p[p] = i;
    srid_p[p] = r;
}

// ---------------------------------------------------------------------------
// k1: one 16-slot rule-uniform strip per block; wave w = K-quarter.
// x from global, prefetch ring depth 5 (6 slots, static indices).
// Outputs: t_bf[slot][64] bf16 (K-padded), hs[slot][32][8] bf16 (sel-scaled).
// ---------------------------------------------------------------------------
__global__ __launch_bounds__(256, 4)
void k1(const float* __restrict__ x,
        const int* __restrict__ perm_p,
        const int* __restrict__ srid_p,
        const unsigned short* __restrict__ ssb,
        const unsigned short* __restrict__ rinf,
        const float* __restrict__ sel_t,
        const int* __restrict__ ntot,
        unsigned short* __restrict__ t_bf,
        unsigned short* __restrict__ hs)
{
    __shared__ __align__(16) float tred[4][16][52];            // 13.3 KB
    __shared__ __align__(16) unsigned short hs_lds[16 * 264];  // 8.45 KB

    const int slot0 = blockIdx.x * 16;
    if (slot0 >= *ntot) return;

    const int tid  = threadIdx.x;
    const int lane = tid & 63;
    const int w    = tid >> 6;            // K-quarter
    const int row_l = lane & 15, grp = lane >> 4;

    const int rid_u = __builtin_amdgcn_readfirstlane(srid_p[slot0]);
    int tok = perm_p[slot0 + row_l];
    if (tok < 0) tok = 0;

    const float* __restrict__ xr = x + (size_t)tok * INF + w * 512 + (grp << 3);
    const unsigned short* __restrict__ sbase =
        ssb + (size_t)(w * 16) * 1536 + lane * 8;
    const bf16x8 ri0 = *(const bf16x8*)(rinf + ((size_t)rid_u * 2 + 0) * 512 + lane * 8);
    const bf16x8 ri1 = *(const bf16x8*)(rinf + ((size_t)rid_u * 2 + 1) * 512 + lane * 8);

    f32x4 aT0 = {0.f, 0.f, 0.f, 0.f};
    f32x4 aT1 = {0.f, 0.f, 0.f, 0.f};
    f32x4 aT2 = {0.f, 0.f, 0.f, 0.f};
    f32x4 aH  = {0.f, 0.f, 0.f, 0.f};

    float4 xa[6][2];                       // ring, depth 5
    bf16x8 wr[2][3];
#pragma unroll
    for (int s_ = 0; s_ < 5; ++s_) {
        xa[s_][0] = *(const float4*)(xr + s_ * 32);
        xa[s_][1] = *(const float4*)(xr + s_ * 32 + 4);
    }
    wr[0][0] = *(const bf16x8*)(sbase);
    wr[0][1] = *(const bf16x8*)(sbase + 512);
    wr[0][2] = *(const bf16x8*)(sbase + 1024);
    SBAR();

#pragma unroll
    for (int c = 0; c < 16; ++c) {
        if (c < 11) {                      // x prefetch, 5 steps ahead
            xa[(c + 5) % 6][0] = *(const float4*)(xr + (c + 5) * 32);
            xa[(c + 5) % 6][1] = *(const float4*)(xr + (c + 5) * 32 + 4);
        }
        if (c < 15) {                      // weights, double-buffered (L2-hot)
            const unsigned short* sp = sbase + (size_t)(c + 1) * 1536;
            wr[(c + 1) & 1][0] = *(const bf16x8*)(sp);
            wr[(c + 1) & 1][1] = *(const bf16x8*)(sp + 512);
            wr[(c + 1) & 1][2] = *(const bf16x8*)(sp + 1024);
        }
        SBAR();                            // pin issue order: loads before compute
        const bf16x8 af = cvt8(xa[c % 6][0], xa[c % 6][1]);
        aT0 = MFMA(af, wr[c & 1][0], aT0, 0, 0, 0);
        aT1 = MFMA(af, wr[c & 1][1], aT1, 0, 0, 0);
        aT2 = MFMA(af, wr[c & 1][2], aT2, 0, 0, 0);
        aH  = MFMA(af, (c & 1) ? ri1 : ri0, aH, 0, 0, 0);
        if (c & 1) {                       // one 64-col block finished
            const int b = w * 8 + (c >> 1);
            const float sel = sel_t[(size_t)rid_u * NBLK + b];
            if (row_l < RANK) {
#pragma unroll
                for (int q = 0; q < 4; ++q)
                    hs_lds[((grp << 2) + q) * 264 + b * 8 + row_l] =
                        (unsigned short)f2bs(aH[q] * sel);
            }
            aH[0] = 0.f; aH[1] = 0.f; aH[2] = 0.f; aH[3] = 0.f;
        }
        SBAR();
    }

    // t partials -> LDS, reduce across 4 K-quarter waves, store bf16 (pad to 64)
#pragma unroll
    for (int q = 0; q < 4; ++q) {
        const int sl = (grp << 2) + q;
        tred[w][sl][row_l]      = aT0[q];
        tred[w][sl][16 + row_l] = aT1[q];
        tred[w][sl][32 + row_l] = aT2[q];
    }
    __syncthreads();
    {
        const int sl = tid >> 4;           // 0..15
        const int c0 = (tid & 15) << 2;    // 0..60, step 4
        s16x4 v = {0, 0, 0, 0};
        if (c0 < 48) {
#pragma unroll
            for (int j = 0; j < 4; ++j) {
                const float s = tred[0][sl][c0 + j] + tred[1][sl][c0 + j]
                              + tred[2][sl][c0 + j] + tred[3][sl][c0 + j];
                v[j] = f2bs(s);
            }
        }
        *(s16x4*)(t_bf + ((size_t)(slot0 + sl)) * 64 + c0) = v;
    }
    // dump sel-scaled hidden: 16 slots x 256 shorts, coalesced 16B
#pragma unroll
    for (int u = 0; u < 2; ++u) {
        const int f = tid + (u << 8);      // 0..511
        const int sl = f >> 5, j8 = f & 31;
        *(bf16x8*)(hs + ((size_t)(slot0 + sl)) * 256 + j8 * 8) =
            *(const bf16x8*)(&hs_lds[sl * 264 + j8 * 8]);
    }
}

// ---------------------------------------------------------------------------
// k2: out[perm] = t@shared_out + hs@rule_out. Zero LDS; grid = 632 x 4 col-
// quarters; wave (strip s, col-half p) covers 16 slots x 256 cols.
// sob/hs double-buffered one 64-col block ahead.
// ---------------------------------------------------------------------------
__global__ __launch_bounds__(256, 4)
void k2(const unsigned short* __restrict__ t_bf,
        const unsigned short* __restrict__ hs,
        const int* __restrict__ perm_p,
        const int* __restrict__ srid_p,
        const unsigned short* __restrict__ sob,
        const unsigned short* __restrict__ rof,
        const int* __restrict__ ntot,
        float* __restrict__ dummy,
        float* __restrict__ out)
{
    const int bid  = blockIdx.x;
    const int tile = bid >> 2, cq = bid & 3;
    const int slot0 = tile * 32;
    if (slot0 >= *ntot) return;

    const int tid  = threadIdx.x;
    const int lane = tid & 63;
    const int w    = tid >> 6;
    const int s    = w & 1;                // strip
    const int p    = w >> 1;               // col-half within quarter
    const int row_l = lane & 15, grp = lane >> 4;
    const int slotbase = slot0 + s * 16;

    const int rid_u = __builtin_amdgcn_readfirstlane(srid_p[slotbase]);

    const unsigned short* __restrict__ tb =
        t_bf + ((size_t)(slotbase + row_l)) * 64 + (grp << 3);
    const bf16x8 at0 = *(const bf16x8*)(tb);
    const bf16x8 at1 = *(const bf16x8*)(tb + 32);

    bf16x8 rfv[4];
#pragma unroll
    for (int i = 0; i < 4; ++i)
        rfv[i] = *(const bf16x8*)(rof + ((size_t)rid_u * 4 + i) * 512 + lane * 8);

    const int4 pv = *(const int4*)(perm_p + slotbase + (grp << 2));
    float* const orow0 = (pv.x < 0) ? dummy : out + (size_t)pv.x * OUTF;
    float* const orow1 = (pv.y < 0) ? dummy : out + (size_t)pv.y * OUTF;
    float* const orow2 = (pv.z < 0) ? dummy : out + (size_t)pv.z * OUTF;
    float* const orow3 = (pv.w < 0) ? dummy : out + (size_t)pv.w * OUTF;

    const int bb0 = cq * 8 + p * 4;        // first 64-col block of this wave

    bf16x8 sb[2][8];
    bf16x8 ah[2];

#define LOADB(BUF, BI) do { \
        const int _bb = bb0 + (BI); \
        bf16x8 _z = {0, 0, 0, 0, 0, 0, 0, 0}; \
        ah[BUF] = _z; \
        if (lane < 16) \
            ah[BUF] = *(const bf16x8*)(hs + ((size_t)(slotbase + lane)) * 256 + _bb * 8); \
        const unsigned short* _sp = sob + ((size_t)_bb * 4) * 1024 + lane * 8; \
        _Pragma("unroll") \
        for (int _cf = 0; _cf < 4; ++_cf) { \
            sb[BUF][_cf * 2]     = *(const bf16x8*)(_sp + _cf * 1024); \
            sb[BUF][_cf * 2 + 1] = *(const bf16x8*)(_sp + _cf * 1024 + 512); \
        } \
    } while (0)

    LOADB(0, 0);
    SBAR();
#pragma unroll
    for (int bi = 0; bi < 4; ++bi) {
        if (bi < 3) LOADB((bi + 1) & 1, bi + 1);
        SBAR();
        const int bb = bb0 + bi;
#pragma unroll
        for (int cf = 0; cf < 4; ++cf) {
            f32x4 acc = {0.f, 0.f, 0.f, 0.f};
            acc = MFMA(at0, sb[bi & 1][cf * 2],     acc, 0, 0, 0);
            acc = MFMA(at1, sb[bi & 1][cf * 2 + 1], acc, 0, 0, 0);
            acc = MFMA(ah[bi & 1], rfv[cf],         acc, 0, 0, 0);
            const int col = ((bb * 4 + cf) << 4) + row_l;
            orow0[col] = acc[0];
            orow1[col] = acc[1];
            orow2[col] = acc[2];
            orow3[col] = acc[3];
        }
        SBAR();
    }
#undef LOADB
}

extern "C" void kernel_launch(void* const* d_in, const int* in_sizes, int n_in,
                              void* d_out, int out_size, void* d_ws, size_t ws_size,
                              hipStream_t stream)
{
    const float* x          = (const float*)d_in[0];
    const int*   rule_ids   = (const int*)  d_in[1];
    const float* shared_in  = (const float*)d_in[2];
    const float* shared_out = (const float*)d_in[3];
    const float* rule_in    = (const float*)d_in[4];
    const float* rule_out   = (const float*)d_in[5];
    const float* logits     = (const float*)d_in[6];
    float* out = (float*)d_out;

    char* p = (char*)d_ws;
    auto carve = [&p](size_t bytes) {
        char* r = p;
        p += (bytes + 255) & ~(size_t)255;
        return r;
    };
    int*            perm_p = (int*)carve(MAXSLOT * 4);
    int*            srid_p = (int*)carve(MAXSLOT * 4);
    unsigned short* ssb    = (unsigned short*)carve(64 * 3 * 512 * 2);
    unsigned short* sob    = (unsigned short*)carve(128 * 2 * 512 * 2);
    unsigned short* rinf   = (unsigned short*)carve((size_t)NRULE * 2 * 512 * 2);
    unsigned short* rof    = (unsigned short*)carve((size_t)NRULE * 4 * 512 * 2);
    float*          sel_t  = (float*)carve((size_t)NRULE * NBLK * 4);
    int*            ghistp = (int*)carve((size_t)NHIST * NRULE * 4);
    int*            gcnt   = (int*)carve(NRULE * 4);
    int*            ntot   = (int*)carve(4);
    float*          dummy  = (float*)carve((size_t)OUTF * 4);
    unsigned short* t_bf   = (unsigned short*)carve((size_t)MAXSLOT * 64 * 2);
    unsigned short* hs     = (unsigned short*)carve((size_t)MAXSLOT * 256 * 2);

    kprep_a<<<dim3(160), dim3(256), 0, stream>>>(
        rule_ids, shared_in, shared_out, rule_in, rule_out,
        ssb, sob, rinf, rof, ghistp, perm_p, srid_p);
    kprep_scan<<<dim3(1), dim3(256), 0, stream>>>(
        ghistp, logits, gcnt, srid_p, sel_t, ntot);
    kprep_scatter<<<dim3(64), dim3(256), 0, stream>>>(
        rule_ids, gcnt, perm_p, srid_p);
    k1<<<dim3(NTILE16), dim3(256), 0, stream>>>(
        x, perm_p, srid_p, ssb, rinf, sel_t, ntot, t_bf, hs);
    k2<<<dim3(NTILE32 * 4), dim3(256), 0, stream>>>(
        t_bf, hs, perm_p, srid_p, sob, rof, ntot, dummy, out);
}

// Round 8
// 105.977 us; speedup vs baseline: 2.5969x; 1.0029x over previous
//
#include <hip/hip_runtime.h>
#include <hip/hip_bf16.h>
#include <math.h>

#define NTOK  16384
#define INF   2048
#define OUTF  2048
#define SR    45
#define RANK  8
#define BLK   64
#define NBLK  32
#define NRULE 256
#define NHIST 32
#define MAXSLOT (NTOK + NRULE * 15)   // 20224
#define NTILE16 (MAXSLOT / 16)        // 1264 strips of 16 slots
#define NTILE32 (MAXSLOT / 32)        // 632 tiles of 32 slots

typedef __attribute__((ext_vector_type(8))) short bf16x8;
typedef __attribute__((ext_vector_type(4))) float f32x4;
typedef __attribute__((ext_vector_type(4))) short s16x4;

#define MFMA __builtin_amdgcn_mfma_f32_16x16x32_bf16
#define SBAR() __builtin_amdgcn_sched_barrier(0)

__device__ inline short f2bs(float f) {
    __hip_bfloat16 h = __float2bfloat16(f);
    return *reinterpret_cast<short*>(&h);
}
__device__ inline bf16x8 cvt8(const float4& a, const float4& b) {
    bf16x8 r;
    r[0] = f2bs(a.x); r[1] = f2bs(a.y); r[2] = f2bs(a.z); r[3] = f2bs(a.w);
    r[4] = f2bs(b.x); r[5] = f2bs(b.y); r[6] = f2bs(b.z); r[7] = f2bs(b.w);
    return r;
}

// ---------------------------------------------------------------------------
// prep A: blocks 0..127 pack weights into MFMA B-frag layout (bf16);
//         blocks 128..159 per-block histogram slabs + init perm/srid.
// B-frag (16x16x32): lane l holds B[k=(l>>4)*8+j][col=l&15], j=0..7.
// ---------------------------------------------------------------------------
__global__ void kprep_a(const int* __restrict__ rule_ids,
                        const float* __restrict__ shared_in,
                        const float* __restrict__ shared_out,
                        const float* __restrict__ rule_in,
                        const float* __restrict__ rule_out,
                        unsigned short* __restrict__ ssb,   // [64ch][3nf][64][8]
                        unsigned short* __restrict__ sob,   // [128CF][2kc][64][8]
                        unsigned short* __restrict__ rinf,  // [256][2half][64][8]
                        unsigned short* __restrict__ rof,   // [256][4cf][64][8]
                        int* __restrict__ ghist_part,       // [32][256]
                        int* __restrict__ perm_p,
                        int* __restrict__ srid_p)
{
    if (blockIdx.x < 128) {
        const int tid = blockIdx.x * 256 + threadIdx.x;
        const int stride = 128 * 256;
        for (int idx = tid; idx < 64 * 3 * 512; idx += stride) {
            int ch = idx / 1536, rem = idx - ch * 1536;
            int nf = rem / 512;
            int l = (rem >> 3) & 63, j = idx & 7;
            int k = ch * 32 + ((l >> 4) << 3) + j;
            int col = nf * 16 + (l & 15);
            ssb[idx] = (col < SR) ? (unsigned short)f2bs(shared_in[(size_t)k * SR + col]) : 0;
        }
        for (int idx = tid; idx < 128 * 2 * 512; idx += stride) {
            int CF = idx >> 10;
            int kc = (idx >> 9) & 1;
            int l = (idx >> 3) & 63, j = idx & 7;
            int k = kc * 32 + ((l >> 4) << 3) + j;
            int col = CF * 16 + (l & 15);
            sob[idx] = (k < SR) ? (unsigned short)f2bs(shared_out[(size_t)k * OUTF + col]) : 0;
        }
        for (int idx = tid; idx < NRULE * 2 * 512; idx += stride) {
            int rid = idx >> 10;
            int half = (idx >> 9) & 1;
            int l = (idx >> 3) & 63, j = idx & 7;
            int r = l & 15;
            int s = half * 32 + ((l >> 4) << 3) + j;
            rinf[idx] = (r < RANK) ? (unsigned short)f2bs(rule_in[(size_t)rid * 512 + s * RANK + r]) : 0;
        }
        for (int idx = tid; idx < NRULE * 4 * 512; idx += stride) {
            int rid = idx >> 11;
            int cf = (idx >> 9) & 3;
            int l = (idx >> 3) & 63, j = idx & 7;
            int k = ((l >> 4) << 3) + j;
            int c = cf * 16 + (l & 15);
            rof[idx] = (k < RANK) ? (unsigned short)f2bs(rule_out[(size_t)rid * 512 + k * BLK + c]) : 0;
        }
    } else {
        __shared__ int lh[NRULE];
        const int tid = threadIdx.x;
        const int hb = blockIdx.x - 128;          // 0..31
        lh[tid] = 0;
        __syncthreads();
        const int base = hb * 512;
        atomicAdd(&lh[rule_ids[base + tid]], 1);
        atomicAdd(&lh[rule_ids[base + 256 + tid]], 1);
        __syncthreads();
        ghist_part[hb * NRULE + tid] = lh[tid];
        for (int j = tid; j < MAXSLOT / 32; j += 256) {
            int idx = hb * (MAXSLOT / 32) + j;
            perm_p[idx] = -1;
            srid_p[idx] = 0;
        }
    }
}

// ---------------------------------------------------------------------------
// prep B (1 block, 256 thr): sum hist slabs, scan, pad srid, sel, ntot
// ---------------------------------------------------------------------------
__global__ void kprep_scan(const int* __restrict__ ghist_part,
                           const float* __restrict__ logits,
                           int* __restrict__ gcnt,
                           int* __restrict__ srid_p,
                           float* __restrict__ sel_t,
                           int* __restrict__ ntot)
{
    __shared__ int sc[NRULE];
    const int tid = threadIdx.x;
    int h = 0;
#pragma unroll
    for (int b = 0; b < NHIST; ++b) h += ghist_part[b * NRULE + tid];
    const int pd = (h + 15) & ~15;
    sc[tid] = pd;
    for (int off = 1; off < NRULE; off <<= 1) {
        __syncthreads();
        int v = (tid >= off) ? sc[tid - off] : 0;
        __syncthreads();
        sc[tid] += v;
    }
    __syncthreads();
    const int excl = sc[tid] - pd;
    gcnt[tid] = excl;
    for (int q = h; q < pd; ++q) srid_p[excl + q] = tid;
    if (tid == NRULE - 1) *ntot = sc[tid];
    const float invT = 5.65685424949238f;
    const float* __restrict__ lg = logits + (size_t)tid * NBLK;
    float m = -1e30f;
    for (int b = 0; b < NBLK; ++b) m = fmaxf(m, lg[b] * invT);
    float s = 0.0f;
    for (int b = 0; b < NBLK; ++b) s += expf(lg[b] * invT - m);
    const float inv = 1.0f / s;
    for (int b = 0; b < NBLK; ++b)
        sel_t[(size_t)tid * NBLK + b] = expf(lg[b] * invT - m) * inv;
}

// ---------------------------------------------------------------------------
// prep C: scatter tokens to padded slots.
// ---------------------------------------------------------------------------
__global__ void kprep_scatter(const int* __restrict__ rule_ids,
                              int* __restrict__ gcnt,
                              int* __restrict__ perm_p,
                              int* __restrict__ srid_p)
{
    const int i = blockIdx.x * 256 + threadIdx.x;
    const int r = rule_ids[i];
    const int p = atomicAdd(&gcnt[r], 1);
    perm_p[p] = i;
    srid_p[p] = r;
}

// ---------------------------------------------------------------------------
// k1: one 16-slot rule-uniform strip per block; wave w = K-quarter.
// x ring: 5 slots / depth-4 (HBM; TLP covers rest). Weight ring: 3 slots /
// depth-2 (~2 iters wall slack >= L2 latency -- this was the stall).
// Outputs: t_bf[slot][64] bf16 (K-padded), hs[slot][32][8] bf16 (sel-scaled).
// ---------------------------------------------------------------------------
__global__ __launch_bounds__(256, 4)
void k1(const float* __restrict__ x,
        const int* __restrict__ perm_p,
        const int* __restrict__ srid_p,
        const unsigned short* __restrict__ ssb,
        const unsigned short* __restrict__ rinf,
        const float* __restrict__ sel_t,
        const int* __restrict__ ntot,
        unsigned short* __restrict__ t_bf,
        unsigned short* __restrict__ hs)
{
    __shared__ __align__(16) float tred[4][16][52];            // 13.3 KB
    __shared__ __align__(16) unsigned short hs_lds[16 * 264];  // 8.45 KB

    const int slot0 = blockIdx.x * 16;
    if (slot0 >= *ntot) return;

    const int tid  = threadIdx.x;
    const int lane = tid & 63;
    const int w    = tid >> 6;            // K-quarter
    const int row_l = lane & 15, grp = lane >> 4;

    const int rid_u = __builtin_amdgcn_readfirstlane(srid_p[slot0]);
    int tok = perm_p[slot0 + row_l];
    if (tok < 0) tok = 0;

    const float* __restrict__ xr = x + (size_t)tok * INF + w * 512 + (grp << 3);
    const unsigned short* __restrict__ sbase =
        ssb + (size_t)(w * 16) * 1536 + lane * 8;
    const bf16x8 ri0 = *(const bf16x8*)(rinf + ((size_t)rid_u * 2 + 0) * 512 + lane * 8);
    const bf16x8 ri1 = *(const bf16x8*)(rinf + ((size_t)rid_u * 2 + 1) * 512 + lane * 8);

    f32x4 aT0 = {0.f, 0.f, 0.f, 0.f};
    f32x4 aT1 = {0.f, 0.f, 0.f, 0.f};
    f32x4 aT2 = {0.f, 0.f, 0.f, 0.f};
    f32x4 aH  = {0.f, 0.f, 0.f, 0.f};

    float4 xa[5][2];                       // ring, depth 4
    bf16x8 wr[3][3];                       // ring, depth 2 (L2 latency cover)
#pragma unroll
    for (int s_ = 0; s_ < 4; ++s_) {
        xa[s_][0] = *(const float4*)(xr + s_ * 32);
        xa[s_][1] = *(const float4*)(xr + s_ * 32 + 4);
    }
#pragma unroll
    for (int s_ = 0; s_ < 2; ++s_) {
        const unsigned short* sp = sbase + (size_t)s_ * 1536;
        wr[s_][0] = *(const bf16x8*)(sp);
        wr[s_][1] = *(const bf16x8*)(sp + 512);
        wr[s_][2] = *(const bf16x8*)(sp + 1024);
    }
    SBAR();

#pragma unroll
    for (int c = 0; c < 16; ++c) {
        if (c < 12) {                      // x prefetch, 4 steps ahead
            xa[(c + 4) % 5][0] = *(const float4*)(xr + (c + 4) * 32);
            xa[(c + 4) % 5][1] = *(const float4*)(xr + (c + 4) * 32 + 4);
        }
        if (c < 14) {                      // weights, 2 steps ahead (L2-hot)
            const unsigned short* sp = sbase + (size_t)(c + 2) * 1536;
            wr[(c + 2) % 3][0] = *(const bf16x8*)(sp);
            wr[(c + 2) % 3][1] = *(const bf16x8*)(sp + 512);
            wr[(c + 2) % 3][2] = *(const bf16x8*)(sp + 1024);
        }
        SBAR();                            // pin issue order: loads before compute
        const bf16x8 af = cvt8(xa[c % 5][0], xa[c % 5][1]);
        aT0 = MFMA(af, wr[c % 3][0], aT0, 0, 0, 0);
        aT1 = MFMA(af, wr[c % 3][1], aT1, 0, 0, 0);
        aT2 = MFMA(af, wr[c % 3][2], aT2, 0, 0, 0);
        aH  = MFMA(af, (c & 1) ? ri1 : ri0, aH, 0, 0, 0);
        if (c & 1) {                       // one 64-col block finished
            const int b = w * 8 + (c >> 1);
            const float sel = sel_t[(size_t)rid_u * NBLK + b];
            if (row_l < RANK) {
#pragma unroll
                for (int q = 0; q < 4; ++q)
                    hs_lds[((grp << 2) + q) * 264 + b * 8 + row_l] =
                        (unsigned short)f2bs(aH[q] * sel);
            }
            aH[0] = 0.f; aH[1] = 0.f; aH[2] = 0.f; aH[3] = 0.f;
        }
        SBAR();
    }

    // t partials -> LDS, reduce across 4 K-quarter waves, store bf16 (pad to 64)
#pragma unroll
    for (int q = 0; q < 4; ++q) {
        const int sl = (grp << 2) + q;
        tred[w][sl][row_l]      = aT0[q];
        tred[w][sl][16 + row_l] = aT1[q];
        tred[w][sl][32 + row_l] = aT2[q];
    }
    __syncthreads();
    {
        const int sl = tid >> 4;           // 0..15
        const int c0 = (tid & 15) << 2;    // 0..60, step 4
        s16x4 v = {0, 0, 0, 0};
        if (c0 < 48) {
#pragma unroll
            for (int j = 0; j < 4; ++j) {
                const float s = tred[0][sl][c0 + j] + tred[1][sl][c0 + j]
                              + tred[2][sl][c0 + j] + tred[3][sl][c0 + j];
                v[j] = f2bs(s);
            }
        }
        *(s16x4*)(t_bf + ((size_t)(slot0 + sl)) * 64 + c0) = v;
    }
    // dump sel-scaled hidden: 16 slots x 256 shorts, coalesced 16B
#pragma unroll
    for (int u = 0; u < 2; ++u) {
        const int f = tid + (u << 8);      // 0..511
        const int sl = f >> 5, j8 = f & 31;
        *(bf16x8*)(hs + ((size_t)(slot0 + sl)) * 256 + j8 * 8) =
            *(const bf16x8*)(&hs_lds[sl * 264 + j8 * 8]);
    }
}

// ---------------------------------------------------------------------------
// k2: out[perm] = t@shared_out + hs@rule_out. Zero LDS.
// XCD-swizzled grid: cq = (bid&7)>>1 so each XCD touches ONE 128KB sob
// quarter (L2-resident). Flat 16-quad loop, sb ring 4 slots / 3 quads ahead.
// ---------------------------------------------------------------------------
__global__ __launch_bounds__(256, 4)
void k2(const unsigned short* __restrict__ t_bf,
        const unsigned short* __restrict__ hs,
        const int* __restrict__ perm_p,
        const int* __restrict__ srid_p,
        const unsigned short* __restrict__ sob,
        const unsigned short* __restrict__ rof,
        const int* __restrict__ ntot,
        float* __restrict__ dummy,
        float* __restrict__ out)
{
    const int bid  = blockIdx.x;
    const int xcd  = bid & 7;
    const int cq   = xcd >> 1;                       // sob quarter per XCD
    const int tile = ((bid >> 3) << 1) | (xcd & 1);  // 0..631, bijective
    const int slot0 = tile * 32;
    if (slot0 >= *ntot) return;

    const int tid  = threadIdx.x;
    const int lane = tid & 63;
    const int w    = tid >> 6;
    const int s    = w & 1;                // strip
    const int p    = w >> 1;               // col-half within quarter
    const int row_l = lane & 15, grp = lane >> 4;
    const int slotbase = slot0 + s * 16;

    const int rid_u = __builtin_amdgcn_readfirstlane(srid_p[slotbase]);

    const unsigned short* __restrict__ tb =
        t_bf + ((size_t)(slotbase + row_l)) * 64 + (grp << 3);
    const bf16x8 at0 = *(const bf16x8*)(tb);
    const bf16x8 at1 = *(const bf16x8*)(tb + 32);

    bf16x8 rfv[4];
#pragma unroll
    for (int i = 0; i < 4; ++i)
        rfv[i] = *(const bf16x8*)(rof + ((size_t)rid_u * 4 + i) * 512 + lane * 8);

    const int4 pv = *(const int4*)(perm_p + slotbase + (grp << 2));
    float* const orow0 = (pv.x < 0) ? dummy : out + (size_t)pv.x * OUTF;
    float* const orow1 = (pv.y < 0) ? dummy : out + (size_t)pv.y * OUTF;
    float* const orow2 = (pv.z < 0) ? dummy : out + (size_t)pv.z * OUTF;
    float* const orow3 = (pv.w < 0) ? dummy : out + (size_t)pv.w * OUTF;

    // CF(qi) = cq*32 + p*16 + qi, qi = 0..15; bb(qi) = (CF >> 2)
    const int CF0 = cq * 32 + p * 16;
    const unsigned short* __restrict__ sobw = sob + (size_t)CF0 * 1024 + lane * 8;
    const unsigned short* __restrict__ hsw  = hs + ((size_t)(slotbase + (lane & 15))) * 256;
    const int bb0 = CF0 >> 2;

    bf16x8 sb[4][2];                       // quad ring, 3 ahead
    bf16x8 ah[2];                          // block ring, 1 ahead
    const bf16x8 zz = {0, 0, 0, 0, 0, 0, 0, 0};

#define LOADQ(SL, QI) do { \
        const unsigned short* _sp = sobw + (size_t)(QI) * 1024; \
        sb[SL][0] = *(const bf16x8*)(_sp); \
        sb[SL][1] = *(const bf16x8*)(_sp + 512); \
    } while (0)
#define LOADA(SL, BI) do { \
        ah[SL] = zz; \
        if (lane < 16) \
            ah[SL] = *(const bf16x8*)(hsw + (size_t)(bb0 + (BI)) * 8); \
    } while (0)

    LOADQ(0, 0); LOADQ(1, 1); LOADQ(2, 2);
    LOADA(0, 0);
    SBAR();

#pragma unroll
    for (int qi = 0; qi < 16; ++qi) {
        if (qi < 13) LOADQ((qi + 3) & 3, qi + 3);
        if ((qi & 3) == 0 && qi < 12) LOADA(((qi >> 2) + 1) & 1, (qi >> 2) + 1);
        SBAR();
        f32x4 acc = {0.f, 0.f, 0.f, 0.f};
        acc = MFMA(at0, sb[qi & 3][0], acc, 0, 0, 0);
        acc = MFMA(at1, sb[qi & 3][1], acc, 0, 0, 0);
        acc = MFMA(ah[(qi >> 2) & 1], rfv[qi & 3], acc, 0, 0, 0);
        const int col = ((CF0 + qi) << 4) + row_l;
        orow0[col] = acc[0];
        orow1[col] = acc[1];
        orow2[col] = acc[2];
        orow3[col] = acc[3];
        SBAR();
    }
#undef LOADQ
#undef LOADA
}

extern "C" void kernel_launch(void* const* d_in, const int* in_sizes, int n_in,
                              void* d_out, int out_size, void* d_ws, size_t ws_size,
                              hipStream_t stream)
{
    const float* x          = (const float*)d_in[0];
    const int*   rule_ids   = (const int*)  d_in[1];
    const float* shared_in  = (const float*)d_in[2];
    const float* shared_out = (const float*)d_in[3];
    const float* rule_in    = (const float*)d_in[4];
    const float* rule_out   = (const float*)d_in[5];
    const float* logits     = (const float*)d_in[6];
    float* out = (float*)d_out;

    char* p = (char*)d_ws;
    auto carve = [&p](size_t bytes) {
        char* r = p;
        p += (bytes + 255) & ~(size_t)255;
        return r;
    };
    int*            perm_p = (int*)carve(MAXSLOT * 4);
    int*            srid_p = (int*)carve(MAXSLOT * 4);
    unsigned short* ssb    = (unsigned short*)carve(64 * 3 * 512 * 2);
    unsigned short* sob    = (unsigned short*)carve(128 * 2 * 512 * 2);
    unsigned short* rinf   = (unsigned short*)carve((size_t)NRULE * 2 * 512 * 2);
    unsigned short* rof    = (unsigned short*)carve((size_t)NRULE * 4 * 512 * 2);
    float*          sel_t  = (float*)carve((size_t)NRULE * NBLK * 4);
    int*            ghistp = (int*)carve((size_t)NHIST * NRULE * 4);
    int*            gcnt   = (int*)carve(NRULE * 4);
    int*            ntot   = (int*)carve(4);
    float*          dummy  = (float*)carve((size_t)OUTF * 4);
    unsigned short* t_bf   = (unsigned short*)carve((size_t)MAXSLOT * 64 * 2);
    unsigned short* hs     = (unsigned short*)carve((size_t)MAXSLOT * 256 * 2);

    kprep_a<<<dim3(160), dim3(256), 0, stream>>>(
        rule_ids, shared_in, shared_out, rule_in, rule_out,
        ssb, sob, rinf, rof, ghistp, perm_p, srid_p);
    kprep_scan<<<dim3(1), dim3(256), 0, stream>>>(
        ghistp, logits, gcnt, srid_p, sel_t, ntot);
    kprep_scatter<<<dim3(64), dim3(256), 0, stream>>>(
        rule_ids, gcnt, perm_p, srid_p);
    k1<<<dim3(NTILE16), dim3(256), 0, stream>>>(
        x, perm_p, srid_p, ssb, rinf, sel_t, ntot, t_bf, hs);
    k2<<<dim3(NTILE32 * 4), dim3(256), 0, stream>>>(
        t_bf, hs, perm_p, srid_p, sob, rof, ntot, dummy, out);
}